// Round 8
// baseline (4182.113 us; speedup 1.0000x reference)
//
#include <hip/hip_runtime.h>
#include <math.h>

#define BB 48
#define TT 32
#define DD 1024
#define SZ 512
#define NCELLS 528  // 32*33/2

typedef unsigned short u16;
typedef unsigned int u32;
typedef __attribute__((ext_vector_type(8))) short bf16x8;
typedef __attribute__((ext_vector_type(4))) float f32x4;

__device__ __forceinline__ int off_of(int k) { return TT * k - (k * (k - 1)) / 2; }

__device__ __forceinline__ u16 f2bf(float x) {
    u32 u = __float_as_uint(x);
    u32 r = (u + 0x7fffu + ((u >> 16) & 1u)) >> 16;
    return (u16)r;
}
__device__ __forceinline__ float bf2f(u16 h) {
    return __uint_as_float(((u32)h) << 16);
}
__device__ __forceinline__ u32 pack2(u16 a, u16 b) {
    return (u32)a | ((u32)b << 16);
}

// ---------------------------------------------------------------------------
__global__ __launch_bounds__(1024) void zero_counters(int* cnts, int n)
{
    int i = threadIdx.x;
    if (i < n) cnts[i] = 0;
}

// prep_w: Wcat[k][n] (512 x 1536) = [Wtop | Wbot | S] -> WT[n][k] bf16 hi/lo
__global__ __launch_bounds__(256) void prep_w(
    const float* __restrict__ w_comp, const float* __restrict__ s_bil,
    u16* __restrict__ WT_hi, u16* __restrict__ WT_lo)
{
    int idx = blockIdx.x * 256 + threadIdx.x;   // n*512 + k
    int n = idx >> 9, k = idx & 511;
    float w;
    if (n < 512)       w = w_comp[(size_t)k * SZ + n];
    else if (n < 1024) w = w_comp[(size_t)(512 + k) * SZ + (n - 512)];
    else               w = s_bil[(size_t)k * SZ + (n - 1024)];
    u16 hi = f2bf(w);
    u16 lo = f2bf(w - bf2f(hi));
    WT_hi[idx] = hi;
    WT_lo[idx] = lo;
}

// prep_wl: w_leaf[k][n] (1024 x 512) -> WLT[n][k] bf16 hi/lo
__global__ __launch_bounds__(256) void prep_wl(
    const float* __restrict__ w_leaf,
    u16* __restrict__ WLT_hi, u16* __restrict__ WLT_lo)
{
    int idx = blockIdx.x * 256 + threadIdx.x;   // n*1024 + k
    int n = idx >> 10, k = idx & 1023;
    float w = w_leaf[(size_t)k * SZ + n];
    u16 hi = f2bf(w);
    u16 lo = f2bf(w - bf2f(hi));
    WLT_hi[idx] = hi;
    WLT_lo[idx] = lo;
}

// ---------------------------------------------------------------------------
// leaf_mfma: leaf_pre = relu(x @ w_leaf + b_leaf), split-bf16 MFMA.
// Tile 128x64, 4 waves (2x2), wave 64x32, K=1024, BK=32. grid (8, 12).
// ---------------------------------------------------------------------------
__global__ __launch_bounds__(256) void leaf_mfma(
    const float* __restrict__ x,
    const u16* __restrict__ WLT_hi, const u16* __restrict__ WLT_lo,
    const float* __restrict__ b_leaf, float* __restrict__ leaf_pre)
{
    __shared__ u16 Ah[128][40], Al[128][40];
    __shared__ u16 Bh[64][40],  Bl[64][40];

    const int col0 = blockIdx.x * 64;
    const int row0 = blockIdx.y * 128;
    const int t = threadIdx.x;

    const int srow = t >> 1, skh = (t & 1) * 16;
    const float* ap = x + (size_t)(row0 + srow) * DD + skh;
    const int bcol = t >> 2, bch = (t & 3) * 8;
    const u16* bph = WLT_hi + (size_t)(col0 + bcol) * DD + bch;
    const u16* bpl = WLT_lo + (size_t)(col0 + bcol) * DD + bch;

    const int lane = t & 63, wv = t >> 6;
    const int wr = wv >> 1, wc = wv & 1;
    const int l15 = lane & 15, lko = (lane >> 4) * 8;

    f32x4 acc[4][2];
    #pragma unroll
    for (int i = 0; i < 4; ++i)
        #pragma unroll
        for (int j = 0; j < 2; ++j)
            #pragma unroll
            for (int e = 0; e < 4; ++e) acc[i][j][e] = 0.f;

    float4 pa[4];
    uint4 pbh, pbl;
    #pragma unroll
    for (int c = 0; c < 4; ++c) pa[c] = *(const float4*)(ap + c * 4);
    pbh = *(const uint4*)bph;
    pbl = *(const uint4*)bpl;

    for (int k0 = 0; k0 < DD; k0 += 32) {
        u32 wh[8], wl[8];
        #pragma unroll
        for (int c = 0; c < 4; ++c) {
            float xs[4] = {pa[c].x, pa[c].y, pa[c].z, pa[c].w};
            u16 hh[4], ll[4];
            #pragma unroll
            for (int e = 0; e < 4; ++e) {
                hh[e] = f2bf(xs[e]);
                ll[e] = f2bf(xs[e] - bf2f(hh[e]));
            }
            wh[c * 2]     = pack2(hh[0], hh[1]);
            wh[c * 2 + 1] = pack2(hh[2], hh[3]);
            wl[c * 2]     = pack2(ll[0], ll[1]);
            wl[c * 2 + 1] = pack2(ll[2], ll[3]);
        }
        *(uint4*)&Ah[srow][skh]     = make_uint4(wh[0], wh[1], wh[2], wh[3]);
        *(uint4*)&Ah[srow][skh + 8] = make_uint4(wh[4], wh[5], wh[6], wh[7]);
        *(uint4*)&Al[srow][skh]     = make_uint4(wl[0], wl[1], wl[2], wl[3]);
        *(uint4*)&Al[srow][skh + 8] = make_uint4(wl[4], wl[5], wl[6], wl[7]);
        *(uint4*)&Bh[bcol][bch] = pbh;
        *(uint4*)&Bl[bcol][bch] = pbl;
        __syncthreads();

        if (k0 + 32 < DD) {
            #pragma unroll
            for (int c = 0; c < 4; ++c)
                pa[c] = *(const float4*)(ap + k0 + 32 + c * 4);
            pbh = *(const uint4*)(bph + k0 + 32);
            pbl = *(const uint4*)(bpl + k0 + 32);
        }

        bf16x8 fah[4], fal[4], fbh[2], fbl[2];
        #pragma unroll
        for (int i = 0; i < 4; ++i) {
            fah[i] = *(const bf16x8*)&Ah[wr * 64 + i * 16 + l15][lko];
            fal[i] = *(const bf16x8*)&Al[wr * 64 + i * 16 + l15][lko];
        }
        #pragma unroll
        for (int j = 0; j < 2; ++j) {
            fbh[j] = *(const bf16x8*)&Bh[wc * 32 + j * 16 + l15][lko];
            fbl[j] = *(const bf16x8*)&Bl[wc * 32 + j * 16 + l15][lko];
        }
        #pragma unroll
        for (int i = 0; i < 4; ++i) {
            #pragma unroll
            for (int j = 0; j < 2; ++j) {
                acc[i][j] = __builtin_amdgcn_mfma_f32_16x16x32_bf16(
                    fah[i], fbh[j], acc[i][j], 0, 0, 0);
                acc[i][j] = __builtin_amdgcn_mfma_f32_16x16x32_bf16(
                    fah[i], fbl[j], acc[i][j], 0, 0, 0);
                acc[i][j] = __builtin_amdgcn_mfma_f32_16x16x32_bf16(
                    fal[i], fbh[j], acc[i][j], 0, 0, 0);
            }
        }
        __syncthreads();
    }

    #pragma unroll
    for (int i = 0; i < 4; ++i) {
        int rbase = row0 + wr * 64 + i * 16 + (lane >> 4) * 4;
        #pragma unroll
        for (int j = 0; j < 2; ++j) {
            int gc = col0 + wc * 32 + j * 16 + l15;
            float bc = b_leaf[gc];
            #pragma unroll
            for (int q = 0; q < 4; ++q)
                leaf_pre[(size_t)(rbase + q) * SZ + gc] =
                    fmaxf(acc[i][j][q] + bc, 0.f);
        }
    }
}

// leaf_norm: normalize rows, write chart_h + split Hcur + Sarr=0.
__global__ __launch_bounds__(256) void leaf_norm(
    const float* __restrict__ leaf_pre, float* __restrict__ chart_h,
    u16* __restrict__ Hc_hi, u16* __restrict__ Hc_lo,
    float* __restrict__ Sarr)
{
    const int r = blockIdx.x;               // 0..1535 = b*32+pos
    const int b = r >> 5, pos = r & 31;
    const int t = threadIdx.x, lane = t & 63, wave = t >> 6;
    __shared__ float red[4];

    float2 v = *(const float2*)&leaf_pre[(size_t)r * SZ + 2 * t];
    float sq = v.x * v.x + v.y * v.y;
    #pragma unroll
    for (int o = 32; o; o >>= 1) sq += __shfl_xor(sq, o);
    if (lane == 0) red[wave] = sq;
    __syncthreads();
    float nrm = sqrtf(red[0] + red[1] + red[2] + red[3]);
    float inv = 1.f / fmaxf(nrm, 1e-12f);
    v.x *= inv; v.y *= inv;
    *(float2*)&chart_h[((size_t)b * NCELLS + pos) * SZ + 2 * t] = v;
    u16 hx = f2bf(v.x), hy = f2bf(v.y);
    ((u32*)Hc_hi)[r * 256 + t] = pack2(hx, hy);
    ((u32*)Hc_lo)[r * 256 + t] = pack2(f2bf(v.x - bf2f(hx)), f2bf(v.y - bf2f(hy)));
    if (t == 0) Sarr[(size_t)b * NCELLS + pos] = 0.f;
}

// ---------------------------------------------------------------------------
// transform_mfma (standalone, level 0 only): 64x64 tile, 4 waves, wave 32x32,
// BK=32, XCD-pinned col-tiles. grid = 24 * nrt.
// ---------------------------------------------------------------------------
__global__ __launch_bounds__(256) void transform_mfma(
    const u16* __restrict__ Hc_hi, const u16* __restrict__ Hc_lo,
    const u16* __restrict__ WT_hi, const u16* __restrict__ WT_lo,
    float* __restrict__ ACU, int level, int nrt)
{
    __shared__ u16 Ah[64][40], Al[64][40];
    __shared__ u16 Bh[64][40], Bl[64][40];
    __shared__ int cidx[64];

    const int L = TT - level, rows = BB * L, off = off_of(level);
    const int id = blockIdx.x;
    const int w = (id & 7) * (3 * nrt) + (id >> 3);
    const int ct = w / nrt, rt = w % nrt;
    const int col0 = ct * 64;

    const int t = threadIdx.x;
    if (t < 64) {
        int g = rt * 64 + t;
        cidx[t] = (g < rows) ? ((g / L) * NCELLS + off + (g % L)) : -1;
    }

    const int srow = t >> 2, skc = (t & 3) * 8;
    const u16* aph = Hc_hi + (size_t)(rt * 64 + srow) * SZ + skc;
    const u16* apl = Hc_lo + (size_t)(rt * 64 + srow) * SZ + skc;
    const u16* bph = WT_hi + (size_t)(col0 + srow) * SZ + skc;
    const u16* bpl = WT_lo + (size_t)(col0 + srow) * SZ + skc;

    const int lane = t & 63, wv = t >> 6;
    const int wr = wv >> 1, wc = wv & 1;
    const int l15 = lane & 15, lko = (lane >> 4) * 8;

    f32x4 acc[2][2];
    #pragma unroll
    for (int i = 0; i < 2; ++i)
        #pragma unroll
        for (int j = 0; j < 2; ++j)
            #pragma unroll
            for (int e = 0; e < 4; ++e) acc[i][j][e] = 0.f;

    uint4 pah = *(const uint4*)aph;
    uint4 pal = *(const uint4*)apl;
    uint4 pbh = *(const uint4*)bph;
    uint4 pbl = *(const uint4*)bpl;

    for (int k0 = 0; k0 < SZ; k0 += 32) {
        *(uint4*)&Ah[srow][skc] = pah;
        *(uint4*)&Al[srow][skc] = pal;
        *(uint4*)&Bh[srow][skc] = pbh;
        *(uint4*)&Bl[srow][skc] = pbl;
        __syncthreads();

        if (k0 + 32 < SZ) {
            pah = *(const uint4*)(aph + k0 + 32);
            pal = *(const uint4*)(apl + k0 + 32);
            pbh = *(const uint4*)(bph + k0 + 32);
            pbl = *(const uint4*)(bpl + k0 + 32);
        }

        bf16x8 fah[2], fal[2], fbh[2], fbl[2];
        #pragma unroll
        for (int i = 0; i < 2; ++i) {
            fah[i] = *(const bf16x8*)&Ah[wr * 32 + i * 16 + l15][lko];
            fal[i] = *(const bf16x8*)&Al[wr * 32 + i * 16 + l15][lko];
        }
        #pragma unroll
        for (int j = 0; j < 2; ++j) {
            fbh[j] = *(const bf16x8*)&Bh[wc * 32 + j * 16 + l15][lko];
            fbl[j] = *(const bf16x8*)&Bl[wc * 32 + j * 16 + l15][lko];
        }
        #pragma unroll
        for (int i = 0; i < 2; ++i) {
            #pragma unroll
            for (int j = 0; j < 2; ++j) {
                acc[i][j] = __builtin_amdgcn_mfma_f32_16x16x32_bf16(
                    fah[i], fbh[j], acc[i][j], 0, 0, 0);
                acc[i][j] = __builtin_amdgcn_mfma_f32_16x16x32_bf16(
                    fah[i], fbl[j], acc[i][j], 0, 0, 0);
                acc[i][j] = __builtin_amdgcn_mfma_f32_16x16x32_bf16(
                    fal[i], fbh[j], acc[i][j], 0, 0, 0);
            }
        }
        __syncthreads();
    }

    #pragma unroll
    for (int i = 0; i < 2; ++i) {
        int rbase = wr * 32 + i * 16 + (lane >> 4) * 4;
        #pragma unroll
        for (int j = 0; j < 2; ++j) {
            int gc = col0 + wc * 32 + j * 16 + l15;
            #pragma unroll
            for (int q = 0; q < 4; ++q) {
                int ci = cidx[rbase + q];
                if (ci >= 0)
                    ACU[(size_t)ci * 1536 + gc] = acc[i][j][q];
            }
        }
    }
}

// ---------------------------------------------------------------------------
// level_fused: combine + transform for one level in a single launch.
// grid = C + T blocks. Ticket [0,C) -> combine cell; [C,C+T) -> transform
// tile, spinning on per-row-tile counters released by combine blocks.
// ---------------------------------------------------------------------------
struct ShCombine {
    float s_lds[32], p_lds[32];
    int lcell[32], rcell[32];
    float hred[4][512];
    float red[4];
};
struct ShTransform {
    u16 Ah[64][40], Al[64][40];
    u16 Bh[64][40], Bl[64][40];
    int cidx[64];
};

__global__ __launch_bounds__(256) void level_fused(
    float* __restrict__ chart_h, float* __restrict__ ACU,
    float* __restrict__ Sarr, const float* __restrict__ b_comp,
    u16* __restrict__ Hc_hi, u16* __restrict__ Hc_lo,
    const u16* __restrict__ WT_hi, const u16* __restrict__ WT_lo,
    int level, int nrt, int* __restrict__ tktctr, int* __restrict__ tilecnt)
{
    __shared__ union { ShCombine c; ShTransform tr; } sh;
    __shared__ int tks;

    const int L = TT - level, N = level, C = BB * L;
    const int off = off_of(level);
    const int t = threadIdx.x;

    if (t == 0)
        tks = __hip_atomic_fetch_add(tktctr, 1, __ATOMIC_RELAXED,
                                     __HIP_MEMORY_SCOPE_AGENT);
    __syncthreads();
    const int tk = tks;

    if (tk < C) {
        // ------------------------------ combine for cell tk = b*L + pos
        const int b = tk / L, pos = tk % L;
        const int lane = t & 63, wv = t >> 6;

        if (t < N) {
            sh.c.lcell[t] = b * NCELLS + off_of(t) + pos;
            sh.c.rcell[t] = b * NCELLS + off_of(level - t - 1) + pos + t + 1;
        }
        __syncthreads();

        // phase 1: s_n = u_l . h_r + s_l + s_r
        for (int n = wv; n < N; n += 4) {
            const float* u  = ACU + (size_t)sh.c.lcell[n] * 1536 + 1024;
            const float* hr = chart_h + (size_t)sh.c.rcell[n] * SZ;
            float d0 = 0.f, d1 = 0.f, d2 = 0.f, d3 = 0.f;
            int j = lane * 2;
            {
                float2 uv = *(const float2*)&u[j];
                float2 hv = *(const float2*)&hr[j];
                d0 = fmaf(uv.x, hv.x, fmaf(uv.y, hv.y, d0));
            }
            {
                float2 uv = *(const float2*)&u[j + 128];
                float2 hv = *(const float2*)&hr[j + 128];
                d1 = fmaf(uv.x, hv.x, fmaf(uv.y, hv.y, d1));
            }
            {
                float2 uv = *(const float2*)&u[j + 256];
                float2 hv = *(const float2*)&hr[j + 256];
                d2 = fmaf(uv.x, hv.x, fmaf(uv.y, hv.y, d2));
            }
            {
                float2 uv = *(const float2*)&u[j + 384];
                float2 hv = *(const float2*)&hr[j + 384];
                d3 = fmaf(uv.x, hv.x, fmaf(uv.y, hv.y, d3));
            }
            float d = (d0 + d1) + (d2 + d3);
            #pragma unroll
            for (int o = 32; o; o >>= 1) d += __shfl_xor(d, o);
            if (lane == 0)
                sh.c.s_lds[n] = d + Sarr[sh.c.lcell[n]] + Sarr[sh.c.rcell[n]];
        }
        __syncthreads();

        // phase 1b: softmax + sbar (wave 0)
        if (wv == 0) {
            float sv = (lane < N) ? sh.c.s_lds[lane] : -INFINITY;
            float m = sv;
            #pragma unroll
            for (int o = 32; o; o >>= 1) m = fmaxf(m, __shfl_xor(m, o));
            float e = (lane < N) ? expf(sv - m) : 0.f;
            float sum = e;
            #pragma unroll
            for (int o = 32; o; o >>= 1) sum += __shfl_xor(sum, o);
            float p = e / sum;
            if (lane < N) sh.c.p_lds[lane] = p;
            float sb = (lane < N) ? sv * p : 0.f;
            #pragma unroll
            for (int o = 32; o; o >>= 1) sb += __shfl_xor(sb, o);
            if (lane == 0) Sarr[(size_t)b * NCELLS + off + pos] = sb;
        }
        __syncthreads();

        // phase 2: per-wave partial hbar
        float ax[4], ay[4];
        float2 bc[4];
        #pragma unroll
        for (int q = 0; q < 4; ++q) {
            ax[q] = 0.f; ay[q] = 0.f;
            bc[q] = *(const float2*)&b_comp[lane * 2 + q * 128];
        }
        for (int n = wv; n < N; n += 4) {
            const float* A_ = ACU + (size_t)sh.c.lcell[n] * 1536;
            const float* C_ = ACU + (size_t)sh.c.rcell[n] * 1536 + 512;
            float p = sh.c.p_lds[n];
            #pragma unroll
            for (int q = 0; q < 4; ++q) {
                int j = lane * 2 + q * 128;
                float2 va = *(const float2*)&A_[j];
                float2 vc = *(const float2*)&C_[j];
                ax[q] = fmaf(p, fmaxf(va.x + vc.x + bc[q].x, 0.f), ax[q]);
                ay[q] = fmaf(p, fmaxf(va.y + vc.y + bc[q].y, 0.f), ay[q]);
            }
        }
        #pragma unroll
        for (int q = 0; q < 4; ++q)
            *(float2*)&sh.c.hred[wv][lane * 2 + q * 128] = make_float2(ax[q], ay[q]);
        __syncthreads();

        float hx = sh.c.hred[0][2 * t] + sh.c.hred[1][2 * t]
                 + sh.c.hred[2][2 * t] + sh.c.hred[3][2 * t];
        float hy = sh.c.hred[0][2 * t + 1] + sh.c.hred[1][2 * t + 1]
                 + sh.c.hred[2][2 * t + 1] + sh.c.hred[3][2 * t + 1];

        float sq = hx * hx + hy * hy;
        #pragma unroll
        for (int o = 32; o; o >>= 1) sq += __shfl_xor(sq, o);
        if (lane == 0) sh.c.red[wv] = sq;
        __syncthreads();
        float nrm = sqrtf(sh.c.red[0] + sh.c.red[1] + sh.c.red[2] + sh.c.red[3]);
        float inv = 1.f / fmaxf(nrm, 1e-12f);
        hx *= inv; hy *= inv;
        size_t obase = ((size_t)b * NCELLS + off + pos) * SZ;
        *(float2*)&chart_h[obase + 2 * t] = make_float2(hx, hy);
        u16 hhx = f2bf(hx), hhy = f2bf(hy);
        ((u32*)Hc_hi)[tk * 256 + t] = pack2(hhx, hhy);
        ((u32*)Hc_lo)[tk * 256 + t] =
            pack2(f2bf(hx - bf2f(hhx)), f2bf(hy - bf2f(hhy)));

        // release: this cell's Hc row is ready
        __syncthreads();
        if (t == 0) {
            __threadfence();
            __hip_atomic_fetch_add(&tilecnt[tk >> 6], 1, __ATOMIC_RELEASE,
                                   __HIP_MEMORY_SCOPE_AGENT);
        }
    } else {
        // ------------------------------ transform tile
        const int id = tk - C;
        const int w = (id & 7) * (3 * nrt) + (id >> 3);
        const int ct = w / nrt, rt = w % nrt;
        const int col0 = ct * 64;
        const int rows = C;

        if (t < 64) {
            int g = rt * 64 + t;
            sh.tr.cidx[t] = (g < rows) ? ((g / L) * NCELLS + off + (g % L)) : -1;
        }

        const int srow = t >> 2, skc = (t & 3) * 8;
        const u16* aph = Hc_hi + (size_t)(rt * 64 + srow) * SZ + skc;
        const u16* apl = Hc_lo + (size_t)(rt * 64 + srow) * SZ + skc;
        const u16* bph = WT_hi + (size_t)(col0 + srow) * SZ + skc;
        const u16* bpl = WT_lo + (size_t)(col0 + srow) * SZ + skc;

        // prefetch static W panel while waiting
        uint4 pbh = *(const uint4*)bph;
        uint4 pbl = *(const uint4*)bpl;

        const int need = min(64, rows - rt * 64);
        if (t == 0) {
            while (__hip_atomic_load(&tilecnt[rt], __ATOMIC_ACQUIRE,
                                     __HIP_MEMORY_SCOPE_AGENT) < need)
                __builtin_amdgcn_s_sleep(2);
        }
        __syncthreads();

        const int lane = t & 63, wv = t >> 6;
        const int wr = wv >> 1, wc = wv & 1;
        const int l15 = lane & 15, lko = (lane >> 4) * 8;

        f32x4 acc[2][2];
        #pragma unroll
        for (int i = 0; i < 2; ++i)
            #pragma unroll
            for (int j = 0; j < 2; ++j)
                #pragma unroll
                for (int e = 0; e < 4; ++e) acc[i][j][e] = 0.f;

        uint4 pah = *(const uint4*)aph;
        uint4 pal = *(const uint4*)apl;

        for (int k0 = 0; k0 < SZ; k0 += 32) {
            *(uint4*)&sh.tr.Ah[srow][skc] = pah;
            *(uint4*)&sh.tr.Al[srow][skc] = pal;
            *(uint4*)&sh.tr.Bh[srow][skc] = pbh;
            *(uint4*)&sh.tr.Bl[srow][skc] = pbl;
            __syncthreads();

            if (k0 + 32 < SZ) {
                pah = *(const uint4*)(aph + k0 + 32);
                pal = *(const uint4*)(apl + k0 + 32);
                pbh = *(const uint4*)(bph + k0 + 32);
                pbl = *(const uint4*)(bpl + k0 + 32);
            }

            bf16x8 fah[2], fal[2], fbh[2], fbl[2];
            #pragma unroll
            for (int i = 0; i < 2; ++i) {
                fah[i] = *(const bf16x8*)&sh.tr.Ah[wr * 32 + i * 16 + l15][lko];
                fal[i] = *(const bf16x8*)&sh.tr.Al[wr * 32 + i * 16 + l15][lko];
            }
            #pragma unroll
            for (int j = 0; j < 2; ++j) {
                fbh[j] = *(const bf16x8*)&sh.tr.Bh[wc * 32 + j * 16 + l15][lko];
                fbl[j] = *(const bf16x8*)&sh.tr.Bl[wc * 32 + j * 16 + l15][lko];
            }
            #pragma unroll
            for (int i = 0; i < 2; ++i) {
                #pragma unroll
                for (int j = 0; j < 2; ++j) {
                    acc[i][j] = __builtin_amdgcn_mfma_f32_16x16x32_bf16(
                        fah[i], fbh[j], acc[i][j], 0, 0, 0);
                    acc[i][j] = __builtin_amdgcn_mfma_f32_16x16x32_bf16(
                        fah[i], fbl[j], acc[i][j], 0, 0, 0);
                    acc[i][j] = __builtin_amdgcn_mfma_f32_16x16x32_bf16(
                        fal[i], fbh[j], acc[i][j], 0, 0, 0);
                }
            }
            __syncthreads();
        }

        #pragma unroll
        for (int i = 0; i < 2; ++i) {
            int rbase = wr * 32 + i * 16 + (lane >> 4) * 4;
            #pragma unroll
            for (int j = 0; j < 2; ++j) {
                int gc = col0 + wc * 32 + j * 16 + l15;
                #pragma unroll
                for (int q = 0; q < 4; ++q) {
                    int ci = sh.tr.cidx[rbase + q];
                    if (ci >= 0)
                        ACU[(size_t)ci * 1536 + gc] = acc[i][j][q];
                }
            }
        }
    }
}

// ---------------------------------------------------------------------------
extern "C" void kernel_launch(void* const* d_in, const int* in_sizes, int n_in,
                              void* d_out, int out_size, void* d_ws, size_t ws_size,
                              hipStream_t stream)
{
    const float* x      = (const float*)d_in[0];
    const float* w_leaf = (const float*)d_in[1];
    const float* b_leaf = (const float*)d_in[2];
    const float* w_comp = (const float*)d_in[3];
    const float* b_comp = (const float*)d_in[4];
    const float* s_bil  = (const float*)d_in[5];
    float* chart_h = (float*)d_out;

    char* ws = (char*)d_ws;
    float* ACU  = (float*)ws;                      ws += (size_t)BB * NCELLS * 1536 * 4;
    float* Sarr = (float*)ws;                      ws += (size_t)BB * NCELLS * 4;
    u16* WT_hi  = (u16*)ws;                        ws += (size_t)1536 * SZ * 2;
    u16* WT_lo  = (u16*)ws;                        ws += (size_t)1536 * SZ * 2;
    u16* WLT_hi = (u16*)ws;                        ws += (size_t)SZ * DD * 2;
    u16* WLT_lo = (u16*)ws;                        ws += (size_t)SZ * DD * 2;
    u16* Hc_hi  = (u16*)ws;                        ws += (size_t)BB * TT * SZ * 2;
    u16* Hc_lo  = (u16*)ws;                        ws += (size_t)BB * TT * SZ * 2;
    float* leaf_pre = (float*)ws;                  ws += (size_t)BB * TT * SZ * 4;
    int* cnts   = (int*)ws;                        // 31 tickets + 31*24 tile ctrs

    const int NCNT = 31 + 31 * 24;
    zero_counters<<<1, 1024, 0, stream>>>(cnts, NCNT);
    prep_w<<<(1536 * SZ) / 256, 256, 0, stream>>>(w_comp, s_bil, WT_hi, WT_lo);
    prep_wl<<<(SZ * DD) / 256, 256, 0, stream>>>(w_leaf, WLT_hi, WLT_lo);
    leaf_mfma<<<dim3(8, 12), 256, 0, stream>>>(x, WLT_hi, WLT_lo, b_leaf, leaf_pre);
    leaf_norm<<<BB * TT, 256, 0, stream>>>(leaf_pre, chart_h, Hc_hi, Hc_lo, Sarr);

    {
        int nrt = (BB * TT + 63) / 64;   // 24
        transform_mfma<<<24 * nrt, 256, 0, stream>>>(
            Hc_hi, Hc_lo, WT_hi, WT_lo, ACU, 0, nrt);
    }

    for (int level = 1; level < TT; ++level) {
        int L = TT - level;
        int C = BB * L;
        int nrt = (C + 63) / 64;
        int T = (level < TT - 1) ? 24 * nrt : 0;
        level_fused<<<C + T, 256, 0, stream>>>(
            chart_h, ACU, Sarr, b_comp, Hc_hi, Hc_lo, WT_hi, WT_lo,
            level, nrt, cnts + (level - 1), cnts + 31 + (level - 1) * 24);
    }
}

// Round 9
// 798.706 us; speedup vs baseline: 5.2361x; 5.2361x over previous
//
#include <hip/hip_runtime.h>
#include <math.h>

#define BB 48
#define TT 32
#define DD 1024
#define SZ 512
#define NCELLS 528  // 32*33/2

typedef unsigned short u16;
typedef unsigned int u32;
typedef __attribute__((ext_vector_type(8))) short bf16x8;
typedef __attribute__((ext_vector_type(4))) float f32x4;

__device__ __forceinline__ int off_of(int k) { return TT * k - (k * (k - 1)) / 2; }

__device__ __forceinline__ u16 f2bf(float x) {
    u32 u = __float_as_uint(x);
    u32 r = (u + 0x7fffu + ((u >> 16) & 1u)) >> 16;
    return (u16)r;
}
__device__ __forceinline__ float bf2f(u16 h) {
    return __uint_as_float(((u32)h) << 16);
}
__device__ __forceinline__ u32 pack2(u16 a, u16 b) {
    return (u32)a | ((u32)b << 16);
}

// ---------------------------------------------------------------------------
// prep_w: Wcat[k][n] (512 x 1536) = [Wtop | Wbot | S] -> WT[n][k] bf16 hi/lo
// (weights keep the hi/lo split; only the activation side is plain bf16)
// ---------------------------------------------------------------------------
__global__ __launch_bounds__(256) void prep_w(
    const float* __restrict__ w_comp, const float* __restrict__ s_bil,
    u16* __restrict__ WT_hi, u16* __restrict__ WT_lo)
{
    int idx = blockIdx.x * 256 + threadIdx.x;   // n*512 + k
    int n = idx >> 9, k = idx & 511;
    float w;
    if (n < 512)       w = w_comp[(size_t)k * SZ + n];
    else if (n < 1024) w = w_comp[(size_t)(512 + k) * SZ + (n - 512)];
    else               w = s_bil[(size_t)k * SZ + (n - 1024)];
    u16 hi = f2bf(w);
    u16 lo = f2bf(w - bf2f(hi));
    WT_hi[idx] = hi;
    WT_lo[idx] = lo;
}

// prep_wl: w_leaf[k][n] (1024 x 512) -> WLT[n][k] bf16 hi/lo
__global__ __launch_bounds__(256) void prep_wl(
    const float* __restrict__ w_leaf,
    u16* __restrict__ WLT_hi, u16* __restrict__ WLT_lo)
{
    int idx = blockIdx.x * 256 + threadIdx.x;   // n*1024 + k
    int n = idx >> 10, k = idx & 1023;
    float w = w_leaf[(size_t)k * SZ + n];
    u16 hi = f2bf(w);
    u16 lo = f2bf(w - bf2f(hi));
    WLT_hi[idx] = hi;
    WLT_lo[idx] = lo;
}

// ---------------------------------------------------------------------------
// leaf_mfma: leaf_pre = relu(x @ w_leaf + b_leaf).
// x plain bf16; W split hi/lo -> 2 MFMA per (i,j).
// Tile 128x64, 4 waves (2x2), wave 64x32, K=1024, BK=32. grid (8, 12).
// ---------------------------------------------------------------------------
__global__ __launch_bounds__(256) void leaf_mfma(
    const float* __restrict__ x,
    const u16* __restrict__ WLT_hi, const u16* __restrict__ WLT_lo,
    const float* __restrict__ b_leaf, float* __restrict__ leaf_pre)
{
    __shared__ u16 Ah[128][40];
    __shared__ u16 Bh[64][40], Bl[64][40];

    const int col0 = blockIdx.x * 64;
    const int row0 = blockIdx.y * 128;
    const int t = threadIdx.x;

    const int srow = t >> 1, skh = (t & 1) * 16;
    const float* ap = x + (size_t)(row0 + srow) * DD + skh;
    const int bcol = t >> 2, bch = (t & 3) * 8;
    const u16* bph = WLT_hi + (size_t)(col0 + bcol) * DD + bch;
    const u16* bpl = WLT_lo + (size_t)(col0 + bcol) * DD + bch;

    const int lane = t & 63, wv = t >> 6;
    const int wr = wv >> 1, wc = wv & 1;
    const int l15 = lane & 15, lko = (lane >> 4) * 8;

    f32x4 acc[4][2];
    #pragma unroll
    for (int i = 0; i < 4; ++i)
        #pragma unroll
        for (int j = 0; j < 2; ++j)
            #pragma unroll
            for (int e = 0; e < 4; ++e) acc[i][j][e] = 0.f;

    float4 pa[4];
    uint4 pbh, pbl;
    #pragma unroll
    for (int c = 0; c < 4; ++c) pa[c] = *(const float4*)(ap + c * 4);
    pbh = *(const uint4*)bph;
    pbl = *(const uint4*)bpl;

    for (int k0 = 0; k0 < DD; k0 += 32) {
        u32 wh[8];
        #pragma unroll
        for (int c = 0; c < 4; ++c) {
            wh[c * 2]     = pack2(f2bf(pa[c].x), f2bf(pa[c].y));
            wh[c * 2 + 1] = pack2(f2bf(pa[c].z), f2bf(pa[c].w));
        }
        *(uint4*)&Ah[srow][skh]     = make_uint4(wh[0], wh[1], wh[2], wh[3]);
        *(uint4*)&Ah[srow][skh + 8] = make_uint4(wh[4], wh[5], wh[6], wh[7]);
        *(uint4*)&Bh[bcol][bch] = pbh;
        *(uint4*)&Bl[bcol][bch] = pbl;
        __syncthreads();

        if (k0 + 32 < DD) {
            #pragma unroll
            for (int c = 0; c < 4; ++c)
                pa[c] = *(const float4*)(ap + k0 + 32 + c * 4);
            pbh = *(const uint4*)(bph + k0 + 32);
            pbl = *(const uint4*)(bpl + k0 + 32);
        }

        bf16x8 fah[4], fbh[2], fbl[2];
        #pragma unroll
        for (int i = 0; i < 4; ++i)
            fah[i] = *(const bf16x8*)&Ah[wr * 64 + i * 16 + l15][lko];
        #pragma unroll
        for (int j = 0; j < 2; ++j) {
            fbh[j] = *(const bf16x8*)&Bh[wc * 32 + j * 16 + l15][lko];
            fbl[j] = *(const bf16x8*)&Bl[wc * 32 + j * 16 + l15][lko];
        }
        #pragma unroll
        for (int i = 0; i < 4; ++i) {
            #pragma unroll
            for (int j = 0; j < 2; ++j) {
                acc[i][j] = __builtin_amdgcn_mfma_f32_16x16x32_bf16(
                    fah[i], fbh[j], acc[i][j], 0, 0, 0);
                acc[i][j] = __builtin_amdgcn_mfma_f32_16x16x32_bf16(
                    fah[i], fbl[j], acc[i][j], 0, 0, 0);
            }
        }
        __syncthreads();
    }

    #pragma unroll
    for (int i = 0; i < 4; ++i) {
        int rbase = row0 + wr * 64 + i * 16 + (lane >> 4) * 4;
        #pragma unroll
        for (int j = 0; j < 2; ++j) {
            int gc = col0 + wc * 32 + j * 16 + l15;
            float bc = b_leaf[gc];
            #pragma unroll
            for (int q = 0; q < 4; ++q)
                leaf_pre[(size_t)(rbase + q) * SZ + gc] =
                    fmaxf(acc[i][j][q] + bc, 0.f);
        }
    }
}

// leaf_norm: normalize rows, write chart_h + bf16 Hcur + Sarr=0.
__global__ __launch_bounds__(256) void leaf_norm(
    const float* __restrict__ leaf_pre, float* __restrict__ chart_h,
    u16* __restrict__ Hc, float* __restrict__ Sarr)
{
    const int r = blockIdx.x;               // 0..1535 = b*32+pos
    const int b = r >> 5, pos = r & 31;
    const int t = threadIdx.x, lane = t & 63, wave = t >> 6;
    __shared__ float red[4];

    float2 v = *(const float2*)&leaf_pre[(size_t)r * SZ + 2 * t];
    float sq = v.x * v.x + v.y * v.y;
    #pragma unroll
    for (int o = 32; o; o >>= 1) sq += __shfl_xor(sq, o);
    if (lane == 0) red[wave] = sq;
    __syncthreads();
    float nrm = sqrtf(red[0] + red[1] + red[2] + red[3]);
    float inv = 1.f / fmaxf(nrm, 1e-12f);
    v.x *= inv; v.y *= inv;
    *(float2*)&chart_h[((size_t)b * NCELLS + pos) * SZ + 2 * t] = v;
    ((u32*)Hc)[r * 256 + t] = pack2(f2bf(v.x), f2bf(v.y));
    if (t == 0) Sarr[(size_t)b * NCELLS + pos] = 0.f;
}

// ---------------------------------------------------------------------------
// transform_mfma: ACU[cell][0:1536] = h[cell] @ Wcat.
// h plain bf16 (Hc); W split hi/lo -> 2 MFMA per (i,j), 8 per k-step.
// 64x64 tile, 4 waves (2x2), wave 32x32, BK=32, ~15.4 KB LDS,
// XCD-pinned col-tiles. grid = 24 * nrt.
// ---------------------------------------------------------------------------
__global__ __launch_bounds__(256) void transform_mfma(
    const u16* __restrict__ Hc,
    const u16* __restrict__ WT_hi, const u16* __restrict__ WT_lo,
    float* __restrict__ ACU, int level, int nrt)
{
    __shared__ u16 Ah[64][40];
    __shared__ u16 Bh[64][40], Bl[64][40];
    __shared__ int cidx[64];

    const int L = TT - level, rows = BB * L, off = off_of(level);
    const int id = blockIdx.x;
    const int w = (id & 7) * (3 * nrt) + (id >> 3);
    const int ct = w / nrt, rt = w % nrt;
    const int col0 = ct * 64;

    const int t = threadIdx.x;
    if (t < 64) {
        int g = rt * 64 + t;
        cidx[t] = (g < rows) ? ((g / L) * NCELLS + off + (g % L)) : -1;
    }

    const int srow = t >> 2, skc = (t & 3) * 8;
    const u16* aph = Hc + (size_t)(rt * 64 + srow) * SZ + skc;
    const u16* bph = WT_hi + (size_t)(col0 + srow) * SZ + skc;
    const u16* bpl = WT_lo + (size_t)(col0 + srow) * SZ + skc;

    const int lane = t & 63, wv = t >> 6;
    const int wr = wv >> 1, wc = wv & 1;
    const int l15 = lane & 15, lko = (lane >> 4) * 8;

    f32x4 acc[2][2];
    #pragma unroll
    for (int i = 0; i < 2; ++i)
        #pragma unroll
        for (int j = 0; j < 2; ++j)
            #pragma unroll
            for (int e = 0; e < 4; ++e) acc[i][j][e] = 0.f;

    uint4 pah = *(const uint4*)aph;
    uint4 pbh = *(const uint4*)bph;
    uint4 pbl = *(const uint4*)bpl;

    for (int k0 = 0; k0 < SZ; k0 += 32) {
        *(uint4*)&Ah[srow][skc] = pah;
        *(uint4*)&Bh[srow][skc] = pbh;
        *(uint4*)&Bl[srow][skc] = pbl;
        __syncthreads();

        if (k0 + 32 < SZ) {
            pah = *(const uint4*)(aph + k0 + 32);
            pbh = *(const uint4*)(bph + k0 + 32);
            pbl = *(const uint4*)(bpl + k0 + 32);
        }

        bf16x8 fah[2], fbh[2], fbl[2];
        #pragma unroll
        for (int i = 0; i < 2; ++i)
            fah[i] = *(const bf16x8*)&Ah[wr * 32 + i * 16 + l15][lko];
        #pragma unroll
        for (int j = 0; j < 2; ++j) {
            fbh[j] = *(const bf16x8*)&Bh[wc * 32 + j * 16 + l15][lko];
            fbl[j] = *(const bf16x8*)&Bl[wc * 32 + j * 16 + l15][lko];
        }
        #pragma unroll
        for (int i = 0; i < 2; ++i) {
            #pragma unroll
            for (int j = 0; j < 2; ++j) {
                acc[i][j] = __builtin_amdgcn_mfma_f32_16x16x32_bf16(
                    fah[i], fbh[j], acc[i][j], 0, 0, 0);
                acc[i][j] = __builtin_amdgcn_mfma_f32_16x16x32_bf16(
                    fah[i], fbl[j], acc[i][j], 0, 0, 0);
            }
        }
        __syncthreads();
    }

    #pragma unroll
    for (int i = 0; i < 2; ++i) {
        int rbase = wr * 32 + i * 16 + (lane >> 4) * 4;
        #pragma unroll
        for (int j = 0; j < 2; ++j) {
            int gc = col0 + wc * 32 + j * 16 + l15;
            #pragma unroll
            for (int q = 0; q < 4; ++q) {
                int ci = cidx[rbase + q];
                if (ci >= 0)
                    ACU[(size_t)ci * 1536 + gc] = acc[i][j][q];
            }
        }
    }
}

// ---------------------------------------------------------------------------
// Combine: one block per (b, pos). float4 loads; writes chart_h + Hc + Sarr.
// ---------------------------------------------------------------------------
__global__ __launch_bounds__(256) void combine_kernel(
    float* __restrict__ chart_h, const float* __restrict__ ACU,
    float* __restrict__ Sarr, const float* __restrict__ b_comp,
    u16* __restrict__ Hc, int level)
{
    const int L = TT - level, N = level;
    const int b = blockIdx.x / L, pos = blockIdx.x % L;
    const int off = off_of(level);

    __shared__ float s_lds[32], p_lds[32];
    __shared__ int lcell[32], rcell[32];
    __shared__ float hred[4][512];
    __shared__ float red[4];

    const int t = threadIdx.x, lane = t & 63, wv = t >> 6;

    if (t < N) {
        lcell[t] = b * NCELLS + off_of(t) + pos;
        rcell[t] = b * NCELLS + off_of(level - t - 1) + pos + t + 1;
    }
    __syncthreads();

    // phase 1: s_n = u_l . h_r + s_l + s_r  (float4 loads)
    for (int n = wv; n < N; n += 4) {
        const float* u  = ACU + (size_t)lcell[n] * 1536 + 1024;
        const float* hr = chart_h + (size_t)rcell[n] * SZ;
        float d0 = 0.f, d1 = 0.f;
        {
            float4 uv = *(const float4*)&u[lane * 4];
            float4 hv = *(const float4*)&hr[lane * 4];
            d0 = fmaf(uv.x, hv.x, fmaf(uv.y, hv.y,
                 fmaf(uv.z, hv.z, fmaf(uv.w, hv.w, d0))));
        }
        {
            float4 uv = *(const float4*)&u[lane * 4 + 256];
            float4 hv = *(const float4*)&hr[lane * 4 + 256];
            d1 = fmaf(uv.x, hv.x, fmaf(uv.y, hv.y,
                 fmaf(uv.z, hv.z, fmaf(uv.w, hv.w, d1))));
        }
        float d = d0 + d1;
        #pragma unroll
        for (int o = 32; o; o >>= 1) d += __shfl_xor(d, o);
        if (lane == 0)
            s_lds[n] = d + Sarr[lcell[n]] + Sarr[rcell[n]];
    }
    __syncthreads();

    // phase 1b: softmax + sbar (wave 0)
    if (wv == 0) {
        float sv = (lane < N) ? s_lds[lane] : -INFINITY;
        float m = sv;
        #pragma unroll
        for (int o = 32; o; o >>= 1) m = fmaxf(m, __shfl_xor(m, o));
        float e = (lane < N) ? expf(sv - m) : 0.f;
        float sum = e;
        #pragma unroll
        for (int o = 32; o; o >>= 1) sum += __shfl_xor(sum, o);
        float p = e / sum;
        if (lane < N) p_lds[lane] = p;
        float sb = (lane < N) ? sv * p : 0.f;
        #pragma unroll
        for (int o = 32; o; o >>= 1) sb += __shfl_xor(sb, o);
        if (lane == 0) Sarr[(size_t)b * NCELLS + off + pos] = sb;
    }
    __syncthreads();

    // phase 2: per-wave partial hbar (float4)
    float4 hacc[2];
    float4 bc[2];
    #pragma unroll
    for (int q = 0; q < 2; ++q) {
        hacc[q] = make_float4(0.f, 0.f, 0.f, 0.f);
        bc[q] = *(const float4*)&b_comp[lane * 4 + q * 256];
    }
    for (int n = wv; n < N; n += 4) {
        const float* A_ = ACU + (size_t)lcell[n] * 1536;
        const float* C_ = ACU + (size_t)rcell[n] * 1536 + 512;
        float p = p_lds[n];
        #pragma unroll
        for (int q = 0; q < 2; ++q) {
            int j = lane * 4 + q * 256;
            float4 va = *(const float4*)&A_[j];
            float4 vc = *(const float4*)&C_[j];
            hacc[q].x = fmaf(p, fmaxf(va.x + vc.x + bc[q].x, 0.f), hacc[q].x);
            hacc[q].y = fmaf(p, fmaxf(va.y + vc.y + bc[q].y, 0.f), hacc[q].y);
            hacc[q].z = fmaf(p, fmaxf(va.z + vc.z + bc[q].z, 0.f), hacc[q].z);
            hacc[q].w = fmaf(p, fmaxf(va.w + vc.w + bc[q].w, 0.f), hacc[q].w);
        }
    }
    #pragma unroll
    for (int q = 0; q < 2; ++q)
        *(float4*)&hred[wv][lane * 4 + q * 256] = hacc[q];
    __syncthreads();

    float hx = hred[0][2 * t] + hred[1][2 * t] + hred[2][2 * t] + hred[3][2 * t];
    float hy = hred[0][2 * t + 1] + hred[1][2 * t + 1]
             + hred[2][2 * t + 1] + hred[3][2 * t + 1];

    float sq = hx * hx + hy * hy;
    #pragma unroll
    for (int o = 32; o; o >>= 1) sq += __shfl_xor(sq, o);
    if (lane == 0) red[wv] = sq;
    __syncthreads();
    float nrm = sqrtf(red[0] + red[1] + red[2] + red[3]);
    float inv = 1.f / fmaxf(nrm, 1e-12f);
    hx *= inv; hy *= inv;
    size_t obase = ((size_t)b * NCELLS + off + pos) * SZ;
    *(float2*)&chart_h[obase + 2 * t] = make_float2(hx, hy);
    int g = b * L + pos;
    ((u32*)Hc)[g * 256 + t] = pack2(f2bf(hx), f2bf(hy));
}

// ---------------------------------------------------------------------------
extern "C" void kernel_launch(void* const* d_in, const int* in_sizes, int n_in,
                              void* d_out, int out_size, void* d_ws, size_t ws_size,
                              hipStream_t stream)
{
    const float* x      = (const float*)d_in[0];
    const float* w_leaf = (const float*)d_in[1];
    const float* b_leaf = (const float*)d_in[2];
    const float* w_comp = (const float*)d_in[3];
    const float* b_comp = (const float*)d_in[4];
    const float* s_bil  = (const float*)d_in[5];
    float* chart_h = (float*)d_out;

    char* ws = (char*)d_ws;
    float* ACU  = (float*)ws;                      ws += (size_t)BB * NCELLS * 1536 * 4;
    float* Sarr = (float*)ws;                      ws += (size_t)BB * NCELLS * 4;
    u16* WT_hi  = (u16*)ws;                        ws += (size_t)1536 * SZ * 2;
    u16* WT_lo  = (u16*)ws;                        ws += (size_t)1536 * SZ * 2;
    u16* WLT_hi = (u16*)ws;                        ws += (size_t)SZ * DD * 2;
    u16* WLT_lo = (u16*)ws;                        ws += (size_t)SZ * DD * 2;
    u16* Hc     = (u16*)ws;                        ws += (size_t)BB * TT * SZ * 2;
    float* leaf_pre = (float*)ws;                  ws += (size_t)BB * TT * SZ * 4;

    prep_w<<<(1536 * SZ) / 256, 256, 0, stream>>>(w_comp, s_bil, WT_hi, WT_lo);
    prep_wl<<<(SZ * DD) / 256, 256, 0, stream>>>(w_leaf, WLT_hi, WLT_lo);
    leaf_mfma<<<dim3(8, 12), 256, 0, stream>>>(x, WLT_hi, WLT_lo, b_leaf, leaf_pre);
    leaf_norm<<<BB * TT, 256, 0, stream>>>(leaf_pre, chart_h, Hc, Sarr);

    {
        int nrt = (BB * TT + 63) / 64;   // 24
        transform_mfma<<<24 * nrt, 256, 0, stream>>>(
            Hc, WT_hi, WT_lo, ACU, 0, nrt);
    }

    for (int level = 1; level < TT; ++level) {
        int L = TT - level;
        combine_kernel<<<BB * L, 256, 0, stream>>>(
            chart_h, ACU, Sarr, b_comp, Hc, level);
        if (level < TT - 1) {
            int nrt = (BB * L + 63) / 64;
            transform_mfma<<<24 * nrt, 256, 0, stream>>>(
                Hc, WT_hi, WT_lo, ACU, level, nrt);
        }
    }
}

// Round 10
// 688.826 us; speedup vs baseline: 6.0714x; 1.1595x over previous
//
#include <hip/hip_runtime.h>
#include <math.h>

#define BB 48
#define TT 32
#define DD 1024
#define SZ 512
#define NCELLS 528  // 32*33/2

typedef unsigned short u16;
typedef unsigned int u32;
typedef __attribute__((ext_vector_type(8))) short bf16x8;
typedef __attribute__((ext_vector_type(4))) float f32x4;

__device__ __forceinline__ int off_of(int k) { return TT * k - (k * (k - 1)) / 2; }

__device__ __forceinline__ u16 f2bf(float x) {
    u32 u = __float_as_uint(x);
    u32 r = (u + 0x7fffu + ((u >> 16) & 1u)) >> 16;
    return (u16)r;
}
__device__ __forceinline__ float bf2f(u16 h) {
    return __uint_as_float(((u32)h) << 16);
}
__device__ __forceinline__ u32 pack2(u16 a, u16 b) {
    return (u32)a | ((u32)b << 16);
}
// unpack u32 holding 2 bf16 -> (elem0, elem1) as f32
__device__ __forceinline__ float2 upk(u32 v) {
    return make_float2(__uint_as_float(v << 16),
                       __uint_as_float(v & 0xffff0000u));
}

// ---------------------------------------------------------------------------
// prep_w: Wcat[k][n] (512 x 1536) = [Wtop | Wbot | S] -> WT[n][k] bf16 hi/lo
// ---------------------------------------------------------------------------
__global__ __launch_bounds__(256) void prep_w(
    const float* __restrict__ w_comp, const float* __restrict__ s_bil,
    u16* __restrict__ WT_hi, u16* __restrict__ WT_lo)
{
    int idx = blockIdx.x * 256 + threadIdx.x;   // n*512 + k
    int n = idx >> 9, k = idx & 511;
    float w;
    if (n < 512)       w = w_comp[(size_t)k * SZ + n];
    else if (n < 1024) w = w_comp[(size_t)(512 + k) * SZ + (n - 512)];
    else               w = s_bil[(size_t)k * SZ + (n - 1024)];
    u16 hi = f2bf(w);
    u16 lo = f2bf(w - bf2f(hi));
    WT_hi[idx] = hi;
    WT_lo[idx] = lo;
}

// prep_wl: w_leaf[k][n] (1024 x 512) -> WLT[n][k] bf16 hi/lo
__global__ __launch_bounds__(256) void prep_wl(
    const float* __restrict__ w_leaf,
    u16* __restrict__ WLT_hi, u16* __restrict__ WLT_lo)
{
    int idx = blockIdx.x * 256 + threadIdx.x;   // n*1024 + k
    int n = idx >> 10, k = idx & 1023;
    float w = w_leaf[(size_t)k * SZ + n];
    u16 hi = f2bf(w);
    u16 lo = f2bf(w - bf2f(hi));
    WLT_hi[idx] = hi;
    WLT_lo[idx] = lo;
}

// ---------------------------------------------------------------------------
// leaf_mfma: leaf_pre = relu(x @ w_leaf + b_leaf). x plain bf16; W hi/lo.
// Tile 128x64, 4 waves (2x2), wave 64x32, K=1024, BK=32. grid (8, 12).
// ---------------------------------------------------------------------------
__global__ __launch_bounds__(256) void leaf_mfma(
    const float* __restrict__ x,
    const u16* __restrict__ WLT_hi, const u16* __restrict__ WLT_lo,
    const float* __restrict__ b_leaf, float* __restrict__ leaf_pre)
{
    __shared__ u16 Ah[128][40];
    __shared__ u16 Bh[64][40], Bl[64][40];

    const int col0 = blockIdx.x * 64;
    const int row0 = blockIdx.y * 128;
    const int t = threadIdx.x;

    const int srow = t >> 1, skh = (t & 1) * 16;
    const float* ap = x + (size_t)(row0 + srow) * DD + skh;
    const int bcol = t >> 2, bch = (t & 3) * 8;
    const u16* bph = WLT_hi + (size_t)(col0 + bcol) * DD + bch;
    const u16* bpl = WLT_lo + (size_t)(col0 + bcol) * DD + bch;

    const int lane = t & 63, wv = t >> 6;
    const int wr = wv >> 1, wc = wv & 1;
    const int l15 = lane & 15, lko = (lane >> 4) * 8;

    f32x4 acc[4][2];
    #pragma unroll
    for (int i = 0; i < 4; ++i)
        #pragma unroll
        for (int j = 0; j < 2; ++j)
            #pragma unroll
            for (int e = 0; e < 4; ++e) acc[i][j][e] = 0.f;

    float4 pa[4];
    uint4 pbh, pbl;
    #pragma unroll
    for (int c = 0; c < 4; ++c) pa[c] = *(const float4*)(ap + c * 4);
    pbh = *(const uint4*)bph;
    pbl = *(const uint4*)bpl;

    for (int k0 = 0; k0 < DD; k0 += 32) {
        u32 wh[8];
        #pragma unroll
        for (int c = 0; c < 4; ++c) {
            wh[c * 2]     = pack2(f2bf(pa[c].x), f2bf(pa[c].y));
            wh[c * 2 + 1] = pack2(f2bf(pa[c].z), f2bf(pa[c].w));
        }
        *(uint4*)&Ah[srow][skh]     = make_uint4(wh[0], wh[1], wh[2], wh[3]);
        *(uint4*)&Ah[srow][skh + 8] = make_uint4(wh[4], wh[5], wh[6], wh[7]);
        *(uint4*)&Bh[bcol][bch] = pbh;
        *(uint4*)&Bl[bcol][bch] = pbl;
        __syncthreads();

        if (k0 + 32 < DD) {
            #pragma unroll
            for (int c = 0; c < 4; ++c)
                pa[c] = *(const float4*)(ap + k0 + 32 + c * 4);
            pbh = *(const uint4*)(bph + k0 + 32);
            pbl = *(const uint4*)(bpl + k0 + 32);
        }

        bf16x8 fah[4], fbh[2], fbl[2];
        #pragma unroll
        for (int i = 0; i < 4; ++i)
            fah[i] = *(const bf16x8*)&Ah[wr * 64 + i * 16 + l15][lko];
        #pragma unroll
        for (int j = 0; j < 2; ++j) {
            fbh[j] = *(const bf16x8*)&Bh[wc * 32 + j * 16 + l15][lko];
            fbl[j] = *(const bf16x8*)&Bl[wc * 32 + j * 16 + l15][lko];
        }
        #pragma unroll
        for (int i = 0; i < 4; ++i) {
            #pragma unroll
            for (int j = 0; j < 2; ++j) {
                acc[i][j] = __builtin_amdgcn_mfma_f32_16x16x32_bf16(
                    fah[i], fbh[j], acc[i][j], 0, 0, 0);
                acc[i][j] = __builtin_amdgcn_mfma_f32_16x16x32_bf16(
                    fah[i], fbl[j], acc[i][j], 0, 0, 0);
            }
        }
        __syncthreads();
    }

    #pragma unroll
    for (int i = 0; i < 4; ++i) {
        int rbase = row0 + wr * 64 + i * 16 + (lane >> 4) * 4;
        #pragma unroll
        for (int j = 0; j < 2; ++j) {
            int gc = col0 + wc * 32 + j * 16 + l15;
            float bc = b_leaf[gc];
            #pragma unroll
            for (int q = 0; q < 4; ++q)
                leaf_pre[(size_t)(rbase + q) * SZ + gc] =
                    fmaxf(acc[i][j][q] + bc, 0.f);
        }
    }
}

// leaf_norm: normalize rows, write chart_h f32 + Hchart bf16 + Sarr=0.
__global__ __launch_bounds__(256) void leaf_norm(
    const float* __restrict__ leaf_pre, float* __restrict__ chart_h,
    u16* __restrict__ Hchart, float* __restrict__ Sarr)
{
    const int r = blockIdx.x;               // 0..1535 = b*32+pos
    const int b = r >> 5, pos = r & 31;
    const int cell = b * NCELLS + pos;
    const int t = threadIdx.x, lane = t & 63, wave = t >> 6;
    __shared__ float red[4];

    float2 v = *(const float2*)&leaf_pre[(size_t)r * SZ + 2 * t];
    float sq = v.x * v.x + v.y * v.y;
    #pragma unroll
    for (int o = 32; o; o >>= 1) sq += __shfl_xor(sq, o);
    if (lane == 0) red[wave] = sq;
    __syncthreads();
    float nrm = sqrtf(red[0] + red[1] + red[2] + red[3]);
    float inv = 1.f / fmaxf(nrm, 1e-12f);
    v.x *= inv; v.y *= inv;
    *(float2*)&chart_h[(size_t)cell * SZ + 2 * t] = v;
    ((u32*)Hchart)[(size_t)cell * 256 + t] = pack2(f2bf(v.x), f2bf(v.y));
    if (t == 0) Sarr[cell] = 0.f;
}

// ---------------------------------------------------------------------------
// transform_mfma: ACU[cell][0:1536] (bf16) = h[cell] @ Wcat.
// h bf16 from Hchart (cell-indexed); W split hi/lo -> 8 MFMA per k-step.
// 64x64 tile, 4 waves (2x2), wave 32x32, BK=32, XCD-pinned col-tiles.
// grid = 24 * nrt.
// ---------------------------------------------------------------------------
__global__ __launch_bounds__(256) void transform_mfma(
    const u16* __restrict__ Hchart,
    const u16* __restrict__ WT_hi, const u16* __restrict__ WT_lo,
    u16* __restrict__ ACU, int level, int nrt)
{
    __shared__ u16 Ah[64][40];
    __shared__ u16 Bh[64][40], Bl[64][40];
    __shared__ int cidx[64];

    const int L = TT - level, rows = BB * L, off = off_of(level);
    const int id = blockIdx.x;
    const int w = (id & 7) * (3 * nrt) + (id >> 3);
    const int ct = w / nrt, rt = w % nrt;
    const int col0 = ct * 64;

    const int t = threadIdx.x;
    if (t < 64) {
        int g = rt * 64 + t;
        cidx[t] = (g < rows) ? ((g / L) * NCELLS + off + (g % L)) : -1;
    }

    const int srow = t >> 2, skc = (t & 3) * 8;
    int ga = rt * 64 + srow;
    if (ga >= rows) ga = rows - 1;          // clamp: safe read, store guarded
    const int acell = (ga / L) * NCELLS + off + (ga % L);
    const u16* aph = Hchart + (size_t)acell * SZ + skc;
    const u16* bph = WT_hi + (size_t)(col0 + srow) * SZ + skc;
    const u16* bpl = WT_lo + (size_t)(col0 + srow) * SZ + skc;

    const int lane = t & 63, wv = t >> 6;
    const int wr = wv >> 1, wc = wv & 1;
    const int l15 = lane & 15, lko = (lane >> 4) * 8;

    f32x4 acc[2][2];
    #pragma unroll
    for (int i = 0; i < 2; ++i)
        #pragma unroll
        for (int j = 0; j < 2; ++j)
            #pragma unroll
            for (int e = 0; e < 4; ++e) acc[i][j][e] = 0.f;

    uint4 pah = *(const uint4*)aph;
    uint4 pbh = *(const uint4*)bph;
    uint4 pbl = *(const uint4*)bpl;

    for (int k0 = 0; k0 < SZ; k0 += 32) {
        *(uint4*)&Ah[srow][skc] = pah;
        *(uint4*)&Bh[srow][skc] = pbh;
        *(uint4*)&Bl[srow][skc] = pbl;
        __syncthreads();

        if (k0 + 32 < SZ) {
            pah = *(const uint4*)(aph + k0 + 32);
            pbh = *(const uint4*)(bph + k0 + 32);
            pbl = *(const uint4*)(bpl + k0 + 32);
        }

        bf16x8 fah[2], fbh[2], fbl[2];
        #pragma unroll
        for (int i = 0; i < 2; ++i)
            fah[i] = *(const bf16x8*)&Ah[wr * 32 + i * 16 + l15][lko];
        #pragma unroll
        for (int j = 0; j < 2; ++j) {
            fbh[j] = *(const bf16x8*)&Bh[wc * 32 + j * 16 + l15][lko];
            fbl[j] = *(const bf16x8*)&Bl[wc * 32 + j * 16 + l15][lko];
        }
        #pragma unroll
        for (int i = 0; i < 2; ++i) {
            #pragma unroll
            for (int j = 0; j < 2; ++j) {
                acc[i][j] = __builtin_amdgcn_mfma_f32_16x16x32_bf16(
                    fah[i], fbh[j], acc[i][j], 0, 0, 0);
                acc[i][j] = __builtin_amdgcn_mfma_f32_16x16x32_bf16(
                    fah[i], fbl[j], acc[i][j], 0, 0, 0);
            }
        }
        __syncthreads();
    }

    #pragma unroll
    for (int i = 0; i < 2; ++i) {
        int rbase = wr * 32 + i * 16 + (lane >> 4) * 4;
        #pragma unroll
        for (int j = 0; j < 2; ++j) {
            int gc = col0 + wc * 32 + j * 16 + l15;
            #pragma unroll
            for (int q = 0; q < 4; ++q) {
                int ci = cidx[rbase + q];
                if (ci >= 0)
                    ACU[(size_t)ci * 1536 + gc] = f2bf(acc[i][j][q]);
            }
        }
    }
}

// ---------------------------------------------------------------------------
// Combine: one block per (b, pos). bf16 ACU/Hchart reads (uint4 = 8 vals).
// ---------------------------------------------------------------------------
__global__ __launch_bounds__(256) void combine_kernel(
    float* __restrict__ chart_h, const u16* __restrict__ ACU,
    const u16* __restrict__ Hchart,
    float* __restrict__ Sarr, const float* __restrict__ b_comp,
    u16* __restrict__ Hchart_w, int level)
{
    const int L = TT - level, N = level;
    const int b = blockIdx.x / L, pos = blockIdx.x % L;
    const int off = off_of(level);

    __shared__ float s_lds[32], p_lds[32];
    __shared__ int lcell[32], rcell[32];
    __shared__ float hred[4][512];
    __shared__ float red[4];

    const int t = threadIdx.x, lane = t & 63, wv = t >> 6;

    if (t < N) {
        lcell[t] = b * NCELLS + off_of(t) + pos;
        rcell[t] = b * NCELLS + off_of(level - t - 1) + pos + t + 1;
    }
    __syncthreads();

    // phase 1: s_n = u_l . h_r + s_l + s_r  (bf16, 8 vals/lane)
    for (int n = wv; n < N; n += 4) {
        const u16* u  = ACU + (size_t)lcell[n] * 1536 + 1024;
        const u16* hr = Hchart + (size_t)rcell[n] * SZ;
        uint4 uv = *(const uint4*)&u[lane * 8];
        uint4 hv = *(const uint4*)&hr[lane * 8];
        float d = 0.f;
        {
            float2 a = upk(uv.x), h2 = upk(hv.x);
            d = fmaf(a.x, h2.x, fmaf(a.y, h2.y, d));
        }
        {
            float2 a = upk(uv.y), h2 = upk(hv.y);
            d = fmaf(a.x, h2.x, fmaf(a.y, h2.y, d));
        }
        {
            float2 a = upk(uv.z), h2 = upk(hv.z);
            d = fmaf(a.x, h2.x, fmaf(a.y, h2.y, d));
        }
        {
            float2 a = upk(uv.w), h2 = upk(hv.w);
            d = fmaf(a.x, h2.x, fmaf(a.y, h2.y, d));
        }
        #pragma unroll
        for (int o = 32; o; o >>= 1) d += __shfl_xor(d, o);
        if (lane == 0)
            s_lds[n] = d + Sarr[lcell[n]] + Sarr[rcell[n]];
    }
    __syncthreads();

    // phase 1b: softmax + sbar (wave 0)
    if (wv == 0) {
        float sv = (lane < N) ? s_lds[lane] : -INFINITY;
        float m = sv;
        #pragma unroll
        for (int o = 32; o; o >>= 1) m = fmaxf(m, __shfl_xor(m, o));
        float e = (lane < N) ? expf(sv - m) : 0.f;
        float sum = e;
        #pragma unroll
        for (int o = 32; o; o >>= 1) sum += __shfl_xor(sum, o);
        float p = e / sum;
        if (lane < N) p_lds[lane] = p;
        float sb = (lane < N) ? sv * p : 0.f;
        #pragma unroll
        for (int o = 32; o; o >>= 1) sb += __shfl_xor(sb, o);
        if (lane == 0) Sarr[(size_t)b * NCELLS + off + pos] = sb;
    }
    __syncthreads();

    // phase 2: per-wave partial hbar; lane owns 8 consecutive outputs
    float hacc[8];
    float bc[8];
    #pragma unroll
    for (int q = 0; q < 8; ++q) {
        hacc[q] = 0.f;
        bc[q] = b_comp[lane * 8 + q];
    }
    for (int n = wv; n < N; n += 4) {
        const u16* A_ = ACU + (size_t)lcell[n] * 1536;
        const u16* C_ = ACU + (size_t)rcell[n] * 1536 + 512;
        uint4 va = *(const uint4*)&A_[lane * 8];
        uint4 vc = *(const uint4*)&C_[lane * 8];
        float p = p_lds[n];
        const u32 av[4] = {va.x, va.y, va.z, va.w};
        const u32 cv[4] = {vc.x, vc.y, vc.z, vc.w};
        #pragma unroll
        for (int c = 0; c < 4; ++c) {
            float2 a2 = upk(av[c]);
            float2 c2 = upk(cv[c]);
            hacc[c * 2]     = fmaf(p, fmaxf(a2.x + c2.x + bc[c * 2], 0.f),
                                   hacc[c * 2]);
            hacc[c * 2 + 1] = fmaf(p, fmaxf(a2.y + c2.y + bc[c * 2 + 1], 0.f),
                                   hacc[c * 2 + 1]);
        }
    }
    *(float4*)&hred[wv][lane * 8]     = *(float4*)&hacc[0];
    *(float4*)&hred[wv][lane * 8 + 4] = *(float4*)&hacc[4];
    __syncthreads();

    float hx = hred[0][2 * t] + hred[1][2 * t] + hred[2][2 * t] + hred[3][2 * t];
    float hy = hred[0][2 * t + 1] + hred[1][2 * t + 1]
             + hred[2][2 * t + 1] + hred[3][2 * t + 1];

    float sq = hx * hx + hy * hy;
    #pragma unroll
    for (int o = 32; o; o >>= 1) sq += __shfl_xor(sq, o);
    if (lane == 0) red[wv] = sq;
    __syncthreads();
    float nrm = sqrtf(red[0] + red[1] + red[2] + red[3]);
    float inv = 1.f / fmaxf(nrm, 1e-12f);
    hx *= inv; hy *= inv;
    const int ocell = b * NCELLS + off + pos;
    *(float2*)&chart_h[(size_t)ocell * SZ + 2 * t] = make_float2(hx, hy);
    ((u32*)Hchart_w)[(size_t)ocell * 256 + t] = pack2(f2bf(hx), f2bf(hy));
}

// ---------------------------------------------------------------------------
extern "C" void kernel_launch(void* const* d_in, const int* in_sizes, int n_in,
                              void* d_out, int out_size, void* d_ws, size_t ws_size,
                              hipStream_t stream)
{
    const float* x      = (const float*)d_in[0];
    const float* w_leaf = (const float*)d_in[1];
    const float* b_leaf = (const float*)d_in[2];
    const float* w_comp = (const float*)d_in[3];
    const float* b_comp = (const float*)d_in[4];
    const float* s_bil  = (const float*)d_in[5];
    float* chart_h = (float*)d_out;

    char* ws = (char*)d_ws;
    u16* ACU    = (u16*)ws;                        ws += (size_t)BB * NCELLS * 1536 * 2;
    u16* Hchart = (u16*)ws;                        ws += (size_t)BB * NCELLS * SZ * 2;
    float* Sarr = (float*)ws;                      ws += (size_t)BB * NCELLS * 4;
    u16* WT_hi  = (u16*)ws;                        ws += (size_t)1536 * SZ * 2;
    u16* WT_lo  = (u16*)ws;                        ws += (size_t)1536 * SZ * 2;
    u16* WLT_hi = (u16*)ws;                        ws += (size_t)SZ * DD * 2;
    u16* WLT_lo = (u16*)ws;                        ws += (size_t)SZ * DD * 2;
    float* leaf_pre = (float*)ws;                  ws += (size_t)BB * TT * SZ * 4;

    prep_w<<<(1536 * SZ) / 256, 256, 0, stream>>>(w_comp, s_bil, WT_hi, WT_lo);
    prep_wl<<<(SZ * DD) / 256, 256, 0, stream>>>(w_leaf, WLT_hi, WLT_lo);
    leaf_mfma<<<dim3(8, 12), 256, 0, stream>>>(x, WLT_hi, WLT_lo, b_leaf, leaf_pre);
    leaf_norm<<<BB * TT, 256, 0, stream>>>(leaf_pre, chart_h, Hchart, Sarr);

    {
        int nrt = (BB * TT + 63) / 64;   // 24
        transform_mfma<<<24 * nrt, 256, 0, stream>>>(
            Hchart, WT_hi, WT_lo, ACU, 0, nrt);
    }

    for (int level = 1; level < TT; ++level) {
        int L = TT - level;
        combine_kernel<<<BB * L, 256, 0, stream>>>(
            chart_h, ACU, Hchart, Sarr, b_comp, Hchart, level);
        if (level < TT - 1) {
            int nrt = (BB * L + 63) / 64;
            transform_mfma<<<24 * nrt, 256, 0, stream>>>(
                Hchart, WT_hi, WT_lo, ACU, level, nrt);
        }
    }
}

// Round 11
// 654.665 us; speedup vs baseline: 6.3882x; 1.0522x over previous
//
#include <hip/hip_runtime.h>
#include <math.h>

#define BB 48
#define TT 32
#define DD 1024
#define SZ 512
#define NCELLS 528  // 32*33/2

typedef unsigned short u16;
typedef unsigned int u32;
typedef __attribute__((ext_vector_type(8))) short bf16x8;
typedef __attribute__((ext_vector_type(4))) float f32x4;

__device__ __forceinline__ int off_of(int k) { return TT * k - (k * (k - 1)) / 2; }

__device__ __forceinline__ u16 f2bf(float x) {
    u32 u = __float_as_uint(x);
    u32 r = (u + 0x7fffu + ((u >> 16) & 1u)) >> 16;
    return (u16)r;
}
__device__ __forceinline__ float bf2f(u16 h) {
    return __uint_as_float(((u32)h) << 16);
}
__device__ __forceinline__ u32 pack2(u16 a, u16 b) {
    return (u32)a | ((u32)b << 16);
}
// unpack u32 holding 2 bf16 -> (elem0, elem1) as f32
__device__ __forceinline__ float2 upk(u32 v) {
    return make_float2(__uint_as_float(v << 16),
                       __uint_as_float(v & 0xffff0000u));
}

// ---------------------------------------------------------------------------
// prep_w: Wcat[k][n] (512 x 1536) = [Wtop | Wbot | S] -> WT[n][k] plain bf16
// ---------------------------------------------------------------------------
__global__ __launch_bounds__(256) void prep_w(
    const float* __restrict__ w_comp, const float* __restrict__ s_bil,
    u16* __restrict__ WT)
{
    int idx = blockIdx.x * 256 + threadIdx.x;   // n*512 + k
    int n = idx >> 9, k = idx & 511;
    float w;
    if (n < 512)       w = w_comp[(size_t)k * SZ + n];
    else if (n < 1024) w = w_comp[(size_t)(512 + k) * SZ + (n - 512)];
    else               w = s_bil[(size_t)k * SZ + (n - 1024)];
    WT[idx] = f2bf(w);
}

// prep_wl: w_leaf[k][n] (1024 x 512) -> WLT[n][k] bf16 hi/lo (leaf keeps split)
__global__ __launch_bounds__(256) void prep_wl(
    const float* __restrict__ w_leaf,
    u16* __restrict__ WLT_hi, u16* __restrict__ WLT_lo)
{
    int idx = blockIdx.x * 256 + threadIdx.x;   // n*1024 + k
    int n = idx >> 10, k = idx & 1023;
    float w = w_leaf[(size_t)k * SZ + n];
    u16 hi = f2bf(w);
    u16 lo = f2bf(w - bf2f(hi));
    WLT_hi[idx] = hi;
    WLT_lo[idx] = lo;
}

// ---------------------------------------------------------------------------
// leaf_mfma: leaf_pre = relu(x @ w_leaf + b_leaf). x plain bf16; W hi/lo.
// Tile 128x64, 4 waves (2x2), wave 64x32, K=1024, BK=32. grid (8, 12).
// ---------------------------------------------------------------------------
__global__ __launch_bounds__(256) void leaf_mfma(
    const float* __restrict__ x,
    const u16* __restrict__ WLT_hi, const u16* __restrict__ WLT_lo,
    const float* __restrict__ b_leaf, float* __restrict__ leaf_pre)
{
    __shared__ u16 Ah[128][40];
    __shared__ u16 Bh[64][40], Bl[64][40];

    const int col0 = blockIdx.x * 64;
    const int row0 = blockIdx.y * 128;
    const int t = threadIdx.x;

    const int srow = t >> 1, skh = (t & 1) * 16;
    const float* ap = x + (size_t)(row0 + srow) * DD + skh;
    const int bcol = t >> 2, bch = (t & 3) * 8;
    const u16* bph = WLT_hi + (size_t)(col0 + bcol) * DD + bch;
    const u16* bpl = WLT_lo + (size_t)(col0 + bcol) * DD + bch;

    const int lane = t & 63, wv = t >> 6;
    const int wr = wv >> 1, wc = wv & 1;
    const int l15 = lane & 15, lko = (lane >> 4) * 8;

    f32x4 acc[4][2];
    #pragma unroll
    for (int i = 0; i < 4; ++i)
        #pragma unroll
        for (int j = 0; j < 2; ++j)
            #pragma unroll
            for (int e = 0; e < 4; ++e) acc[i][j][e] = 0.f;

    float4 pa[4];
    uint4 pbh, pbl;
    #pragma unroll
    for (int c = 0; c < 4; ++c) pa[c] = *(const float4*)(ap + c * 4);
    pbh = *(const uint4*)bph;
    pbl = *(const uint4*)bpl;

    for (int k0 = 0; k0 < DD; k0 += 32) {
        u32 wh[8];
        #pragma unroll
        for (int c = 0; c < 4; ++c) {
            wh[c * 2]     = pack2(f2bf(pa[c].x), f2bf(pa[c].y));
            wh[c * 2 + 1] = pack2(f2bf(pa[c].z), f2bf(pa[c].w));
        }
        *(uint4*)&Ah[srow][skh]     = make_uint4(wh[0], wh[1], wh[2], wh[3]);
        *(uint4*)&Ah[srow][skh + 8] = make_uint4(wh[4], wh[5], wh[6], wh[7]);
        *(uint4*)&Bh[bcol][bch] = pbh;
        *(uint4*)&Bl[bcol][bch] = pbl;
        __syncthreads();

        if (k0 + 32 < DD) {
            #pragma unroll
            for (int c = 0; c < 4; ++c)
                pa[c] = *(const float4*)(ap + k0 + 32 + c * 4);
            pbh = *(const uint4*)(bph + k0 + 32);
            pbl = *(const uint4*)(bpl + k0 + 32);
        }

        bf16x8 fah[4], fbh[2], fbl[2];
        #pragma unroll
        for (int i = 0; i < 4; ++i)
            fah[i] = *(const bf16x8*)&Ah[wr * 64 + i * 16 + l15][lko];
        #pragma unroll
        for (int j = 0; j < 2; ++j) {
            fbh[j] = *(const bf16x8*)&Bh[wc * 32 + j * 16 + l15][lko];
            fbl[j] = *(const bf16x8*)&Bl[wc * 32 + j * 16 + l15][lko];
        }
        #pragma unroll
        for (int i = 0; i < 4; ++i) {
            #pragma unroll
            for (int j = 0; j < 2; ++j) {
                acc[i][j] = __builtin_amdgcn_mfma_f32_16x16x32_bf16(
                    fah[i], fbh[j], acc[i][j], 0, 0, 0);
                acc[i][j] = __builtin_amdgcn_mfma_f32_16x16x32_bf16(
                    fah[i], fbl[j], acc[i][j], 0, 0, 0);
            }
        }
        __syncthreads();
    }

    #pragma unroll
    for (int i = 0; i < 4; ++i) {
        int rbase = row0 + wr * 64 + i * 16 + (lane >> 4) * 4;
        #pragma unroll
        for (int j = 0; j < 2; ++j) {
            int gc = col0 + wc * 32 + j * 16 + l15;
            float bc = b_leaf[gc];
            #pragma unroll
            for (int q = 0; q < 4; ++q)
                leaf_pre[(size_t)(rbase + q) * SZ + gc] =
                    fmaxf(acc[i][j][q] + bc, 0.f);
        }
    }
}

// leaf_norm: normalize rows, write chart_h f32 + Hchart bf16 + Sarr=0.
__global__ __launch_bounds__(256) void leaf_norm(
    const float* __restrict__ leaf_pre, float* __restrict__ chart_h,
    u16* __restrict__ Hchart, float* __restrict__ Sarr)
{
    const int r = blockIdx.x;               // 0..1535 = b*32+pos
    const int b = r >> 5, pos = r & 31;
    const int cell = b * NCELLS + pos;
    const int t = threadIdx.x, lane = t & 63, wave = t >> 6;
    __shared__ float red[4];

    float2 v = *(const float2*)&leaf_pre[(size_t)r * SZ + 2 * t];
    float sq = v.x * v.x + v.y * v.y;
    #pragma unroll
    for (int o = 32; o; o >>= 1) sq += __shfl_xor(sq, o);
    if (lane == 0) red[wave] = sq;
    __syncthreads();
    float nrm = sqrtf(red[0] + red[1] + red[2] + red[3]);
    float inv = 1.f / fmaxf(nrm, 1e-12f);
    v.x *= inv; v.y *= inv;
    *(float2*)&chart_h[(size_t)cell * SZ + 2 * t] = v;
    ((u32*)Hchart)[(size_t)cell * 256 + t] = pack2(f2bf(v.x), f2bf(v.y));
    if (t == 0) Sarr[cell] = 0.f;
}

// ---------------------------------------------------------------------------
// transform_mfma: ACU[cell][0:1536] (bf16) = h[cell] @ Wcat [+ b_comp on A].
// h bf16 (Hchart); W plain bf16 -> 4 MFMA per k-step.
// 64x64 tile, 4 waves (2x2), wave 32x32, BK=32, ~10.4 KB LDS,
// XCD-pinned col-tiles. grid = 24 * nrt.
// ---------------------------------------------------------------------------
__global__ __launch_bounds__(256) void transform_mfma(
    const u16* __restrict__ Hchart, const u16* __restrict__ WT,
    const float* __restrict__ b_comp,
    u16* __restrict__ ACU, int level, int nrt)
{
    __shared__ u16 Ah[64][40];
    __shared__ u16 Bh[64][40];
    __shared__ int cidx[64];

    const int L = TT - level, rows = BB * L, off = off_of(level);
    const int id = blockIdx.x;
    const int w = (id & 7) * (3 * nrt) + (id >> 3);
    const int ct = w / nrt, rt = w % nrt;
    const int col0 = ct * 64;

    const int t = threadIdx.x;
    if (t < 64) {
        int g = rt * 64 + t;
        cidx[t] = (g < rows) ? ((g / L) * NCELLS + off + (g % L)) : -1;
    }

    const int srow = t >> 2, skc = (t & 3) * 8;
    int ga = rt * 64 + srow;
    if (ga >= rows) ga = rows - 1;          // clamp: safe read, store guarded
    const int acell = (ga / L) * NCELLS + off + (ga % L);
    const u16* aph = Hchart + (size_t)acell * SZ + skc;
    const u16* bph = WT + (size_t)(col0 + srow) * SZ + skc;

    const int lane = t & 63, wv = t >> 6;
    const int wr = wv >> 1, wc = wv & 1;
    const int l15 = lane & 15, lko = (lane >> 4) * 8;

    f32x4 acc[2][2];
    #pragma unroll
    for (int i = 0; i < 2; ++i)
        #pragma unroll
        for (int j = 0; j < 2; ++j)
            #pragma unroll
            for (int e = 0; e < 4; ++e) acc[i][j][e] = 0.f;

    uint4 pah = *(const uint4*)aph;
    uint4 pbh = *(const uint4*)bph;

    for (int k0 = 0; k0 < SZ; k0 += 32) {
        *(uint4*)&Ah[srow][skc] = pah;
        *(uint4*)&Bh[srow][skc] = pbh;
        __syncthreads();

        if (k0 + 32 < SZ) {
            pah = *(const uint4*)(aph + k0 + 32);
            pbh = *(const uint4*)(bph + k0 + 32);
        }

        bf16x8 fah[2], fbh[2];
        #pragma unroll
        for (int i = 0; i < 2; ++i)
            fah[i] = *(const bf16x8*)&Ah[wr * 32 + i * 16 + l15][lko];
        #pragma unroll
        for (int j = 0; j < 2; ++j)
            fbh[j] = *(const bf16x8*)&Bh[wc * 32 + j * 16 + l15][lko];
        #pragma unroll
        for (int i = 0; i < 2; ++i)
            #pragma unroll
            for (int j = 0; j < 2; ++j)
                acc[i][j] = __builtin_amdgcn_mfma_f32_16x16x32_bf16(
                    fah[i], fbh[j], acc[i][j], 0, 0, 0);
        __syncthreads();
    }

    #pragma unroll
    for (int i = 0; i < 2; ++i) {
        int rbase = wr * 32 + i * 16 + (lane >> 4) * 4;
        #pragma unroll
        for (int j = 0; j < 2; ++j) {
            int gc = col0 + wc * 32 + j * 16 + l15;
            float bias = (gc < 512) ? b_comp[gc] : 0.f;  // fold comp bias into A
            #pragma unroll
            for (int q = 0; q < 4; ++q) {
                int ci = cidx[rbase + q];
                if (ci >= 0)
                    ACU[(size_t)ci * 1536 + gc] = f2bf(acc[i][j][q] + bias);
            }
        }
    }
}

// ---------------------------------------------------------------------------
// Combine: one block per (b, pos). bf16 ACU/Hchart reads (uint4 = 8 vals).
// A already carries the comp bias.
// ---------------------------------------------------------------------------
__global__ __launch_bounds__(256) void combine_kernel(
    float* __restrict__ chart_h, const u16* __restrict__ ACU,
    const u16* __restrict__ Hchart,
    float* __restrict__ Sarr, u16* __restrict__ Hchart_w, int level)
{
    const int L = TT - level, N = level;
    const int b = blockIdx.x / L, pos = blockIdx.x % L;
    const int off = off_of(level);

    __shared__ float s_lds[32], p_lds[32];
    __shared__ int lcell[32], rcell[32];
    __shared__ float hred[4][512];
    __shared__ float red[4];

    const int t = threadIdx.x, lane = t & 63, wv = t >> 6;

    if (t < N) {
        lcell[t] = b * NCELLS + off_of(t) + pos;
        rcell[t] = b * NCELLS + off_of(level - t - 1) + pos + t + 1;
    }
    __syncthreads();

    // phase 1: s_n = u_l . h_r + s_l + s_r  (bf16, 8 vals/lane)
    for (int n = wv; n < N; n += 4) {
        const u16* u  = ACU + (size_t)lcell[n] * 1536 + 1024;
        const u16* hr = Hchart + (size_t)rcell[n] * SZ;
        uint4 uv = *(const uint4*)&u[lane * 8];
        uint4 hv = *(const uint4*)&hr[lane * 8];
        float d = 0.f;
        {
            float2 a = upk(uv.x), h2 = upk(hv.x);
            d = fmaf(a.x, h2.x, fmaf(a.y, h2.y, d));
        }
        {
            float2 a = upk(uv.y), h2 = upk(hv.y);
            d = fmaf(a.x, h2.x, fmaf(a.y, h2.y, d));
        }
        {
            float2 a = upk(uv.z), h2 = upk(hv.z);
            d = fmaf(a.x, h2.x, fmaf(a.y, h2.y, d));
        }
        {
            float2 a = upk(uv.w), h2 = upk(hv.w);
            d = fmaf(a.x, h2.x, fmaf(a.y, h2.y, d));
        }
        #pragma unroll
        for (int o = 32; o; o >>= 1) d += __shfl_xor(d, o);
        if (lane == 0)
            s_lds[n] = d + Sarr[lcell[n]] + Sarr[rcell[n]];
    }
    __syncthreads();

    // phase 1b: softmax + sbar (wave 0)
    if (wv == 0) {
        float sv = (lane < N) ? s_lds[lane] : -INFINITY;
        float m = sv;
        #pragma unroll
        for (int o = 32; o; o >>= 1) m = fmaxf(m, __shfl_xor(m, o));
        float e = (lane < N) ? expf(sv - m) : 0.f;
        float sum = e;
        #pragma unroll
        for (int o = 32; o; o >>= 1) sum += __shfl_xor(sum, o);
        float p = e / sum;
        if (lane < N) p_lds[lane] = p;
        float sb = (lane < N) ? sv * p : 0.f;
        #pragma unroll
        for (int o = 32; o; o >>= 1) sb += __shfl_xor(sb, o);
        if (lane == 0) Sarr[(size_t)b * NCELLS + off + pos] = sb;
    }
    __syncthreads();

    // phase 2: per-wave partial hbar; lane owns 8 consecutive outputs
    float hacc[8];
    #pragma unroll
    for (int q = 0; q < 8; ++q) hacc[q] = 0.f;
    for (int n = wv; n < N; n += 4) {
        const u16* A_ = ACU + (size_t)lcell[n] * 1536;
        const u16* C_ = ACU + (size_t)rcell[n] * 1536 + 512;
        uint4 va = *(const uint4*)&A_[lane * 8];
        uint4 vc = *(const uint4*)&C_[lane * 8];
        float p = p_lds[n];
        const u32 av[4] = {va.x, va.y, va.z, va.w};
        const u32 cv[4] = {vc.x, vc.y, vc.z, vc.w};
        #pragma unroll
        for (int c = 0; c < 4; ++c) {
            float2 a2 = upk(av[c]);
            float2 c2 = upk(cv[c]);
            hacc[c * 2]     = fmaf(p, fmaxf(a2.x + c2.x, 0.f), hacc[c * 2]);
            hacc[c * 2 + 1] = fmaf(p, fmaxf(a2.y + c2.y, 0.f), hacc[c * 2 + 1]);
        }
    }
    *(float4*)&hred[wv][lane * 8]     = *(float4*)&hacc[0];
    *(float4*)&hred[wv][lane * 8 + 4] = *(float4*)&hacc[4];
    __syncthreads();

    float hx = hred[0][2 * t] + hred[1][2 * t] + hred[2][2 * t] + hred[3][2 * t];
    float hy = hred[0][2 * t + 1] + hred[1][2 * t + 1]
             + hred[2][2 * t + 1] + hred[3][2 * t + 1];

    float sq = hx * hx + hy * hy;
    #pragma unroll
    for (int o = 32; o; o >>= 1) sq += __shfl_xor(sq, o);
    if (lane == 0) red[wv] = sq;
    __syncthreads();
    float nrm = sqrtf(red[0] + red[1] + red[2] + red[3]);
    float inv = 1.f / fmaxf(nrm, 1e-12f);
    hx *= inv; hy *= inv;
    const int ocell = b * NCELLS + off + pos;
    *(float2*)&chart_h[(size_t)ocell * SZ + 2 * t] = make_float2(hx, hy);
    ((u32*)Hchart_w)[(size_t)ocell * 256 + t] = pack2(f2bf(hx), f2bf(hy));
}

// ---------------------------------------------------------------------------
extern "C" void kernel_launch(void* const* d_in, const int* in_sizes, int n_in,
                              void* d_out, int out_size, void* d_ws, size_t ws_size,
                              hipStream_t stream)
{
    const float* x      = (const float*)d_in[0];
    const float* w_leaf = (const float*)d_in[1];
    const float* b_leaf = (const float*)d_in[2];
    const float* w_comp = (const float*)d_in[3];
    const float* b_comp = (const float*)d_in[4];
    const float* s_bil  = (const float*)d_in[5];
    float* chart_h = (float*)d_out;

    char* ws = (char*)d_ws;
    u16* ACU    = (u16*)ws;                        ws += (size_t)BB * NCELLS * 1536 * 2;
    u16* Hchart = (u16*)ws;                        ws += (size_t)BB * NCELLS * SZ * 2;
    float* Sarr = (float*)ws;                      ws += (size_t)BB * NCELLS * 4;
    u16* WT     = (u16*)ws;                        ws += (size_t)1536 * SZ * 2;
    u16* WLT_hi = (u16*)ws;                        ws += (size_t)SZ * DD * 2;
    u16* WLT_lo = (u16*)ws;                        ws += (size_t)SZ * DD * 2;
    float* leaf_pre = (float*)ws;                  ws += (size_t)BB * TT * SZ * 4;

    prep_w<<<(1536 * SZ) / 256, 256, 0, stream>>>(w_comp, s_bil, WT);
    prep_wl<<<(SZ * DD) / 256, 256, 0, stream>>>(w_leaf, WLT_hi, WLT_lo);
    leaf_mfma<<<dim3(8, 12), 256, 0, stream>>>(x, WLT_hi, WLT_lo, b_leaf, leaf_pre);
    leaf_norm<<<BB * TT, 256, 0, stream>>>(leaf_pre, chart_h, Hchart, Sarr);

    {
        int nrt = (BB * TT + 63) / 64;   // 24
        transform_mfma<<<24 * nrt, 256, 0, stream>>>(
            Hchart, WT, b_comp, ACU, 0, nrt);
    }

    for (int level = 1; level < TT; ++level) {
        int L = TT - level;
        combine_kernel<<<BB * L, 256, 0, stream>>>(
            chart_h, ACU, Hchart, Sarr, Hchart, level);
        if (level < TT - 1) {
            int nrt = (BB * L + 63) / 64;
            transform_mfma<<<24 * nrt, 256, 0, stream>>>(
                Hchart, WT, b_comp, ACU, level, nrt);
        }
    }
}

// Round 12
// 636.525 us; speedup vs baseline: 6.5702x; 1.0285x over previous
//
#include <hip/hip_runtime.h>
#include <math.h>

#define BB 48
#define TT 32
#define DD 1024
#define SZ 512
#define NCELLS 528  // 32*33/2

typedef unsigned short u16;
typedef unsigned int u32;
typedef __attribute__((ext_vector_type(8))) short bf16x8;
typedef __attribute__((ext_vector_type(4))) float f32x4;

__device__ __forceinline__ int off_of(int k) { return TT * k - (k * (k - 1)) / 2; }

__device__ __forceinline__ u16 f2bf(float x) {
    u32 u = __float_as_uint(x);
    u32 r = (u + 0x7fffu + ((u >> 16) & 1u)) >> 16;
    return (u16)r;
}
__device__ __forceinline__ float bf2f(u16 h) {
    return __uint_as_float(((u32)h) << 16);
}
__device__ __forceinline__ u32 pack2(u16 a, u16 b) {
    return (u32)a | ((u32)b << 16);
}
// unpack u32 holding 2 bf16 -> (elem0, elem1) as f32
__device__ __forceinline__ float2 upk(u32 v) {
    return make_float2(__uint_as_float(v << 16),
                       __uint_as_float(v & 0xffff0000u));
}

// ---------------------------------------------------------------------------
// prep_w: Wcat[k][n] (512 x 1536) = [Wtop | Wbot | S] -> WT[n][k] plain bf16
// ---------------------------------------------------------------------------
__global__ __launch_bounds__(256) void prep_w(
    const float* __restrict__ w_comp, const float* __restrict__ s_bil,
    u16* __restrict__ WT)
{
    int idx = blockIdx.x * 256 + threadIdx.x;   // n*512 + k
    int n = idx >> 9, k = idx & 511;
    float w;
    if (n < 512)       w = w_comp[(size_t)k * SZ + n];
    else if (n < 1024) w = w_comp[(size_t)(512 + k) * SZ + (n - 512)];
    else               w = s_bil[(size_t)k * SZ + (n - 1024)];
    WT[idx] = f2bf(w);
}

// prep_wl: w_leaf[k][n] (1024 x 512) -> WLT[n][k] bf16 hi/lo (leaf keeps split)
__global__ __launch_bounds__(256) void prep_wl(
    const float* __restrict__ w_leaf,
    u16* __restrict__ WLT_hi, u16* __restrict__ WLT_lo)
{
    int idx = blockIdx.x * 256 + threadIdx.x;   // n*1024 + k
    int n = idx >> 10, k = idx & 1023;
    float w = w_leaf[(size_t)k * SZ + n];
    u16 hi = f2bf(w);
    u16 lo = f2bf(w - bf2f(hi));
    WLT_hi[idx] = hi;
    WLT_lo[idx] = lo;
}

// ---------------------------------------------------------------------------
// leaf_mfma: leaf_pre = relu(x @ w_leaf + b_leaf). x plain bf16; W hi/lo.
// Tile 128x64, 4 waves (2x2), wave 64x32, K=1024, BK=32. grid (8, 12).
// ---------------------------------------------------------------------------
__global__ __launch_bounds__(256) void leaf_mfma(
    const float* __restrict__ x,
    const u16* __restrict__ WLT_hi, const u16* __restrict__ WLT_lo,
    const float* __restrict__ b_leaf, float* __restrict__ leaf_pre)
{
    __shared__ u16 Ah[128][40];
    __shared__ u16 Bh[64][40], Bl[64][40];

    const int col0 = blockIdx.x * 64;
    const int row0 = blockIdx.y * 128;
    const int t = threadIdx.x;

    const int srow = t >> 1, skh = (t & 1) * 16;
    const float* ap = x + (size_t)(row0 + srow) * DD + skh;
    const int bcol = t >> 2, bch = (t & 3) * 8;
    const u16* bph = WLT_hi + (size_t)(col0 + bcol) * DD + bch;
    const u16* bpl = WLT_lo + (size_t)(col0 + bcol) * DD + bch;

    const int lane = t & 63, wv = t >> 6;
    const int wr = wv >> 1, wc = wv & 1;
    const int l15 = lane & 15, lko = (lane >> 4) * 8;

    f32x4 acc[4][2];
    #pragma unroll
    for (int i = 0; i < 4; ++i)
        #pragma unroll
        for (int j = 0; j < 2; ++j)
            #pragma unroll
            for (int e = 0; e < 4; ++e) acc[i][j][e] = 0.f;

    float4 pa[4];
    uint4 pbh, pbl;
    #pragma unroll
    for (int c = 0; c < 4; ++c) pa[c] = *(const float4*)(ap + c * 4);
    pbh = *(const uint4*)bph;
    pbl = *(const uint4*)bpl;

    for (int k0 = 0; k0 < DD; k0 += 32) {
        u32 wh[8];
        #pragma unroll
        for (int c = 0; c < 4; ++c) {
            wh[c * 2]     = pack2(f2bf(pa[c].x), f2bf(pa[c].y));
            wh[c * 2 + 1] = pack2(f2bf(pa[c].z), f2bf(pa[c].w));
        }
        *(uint4*)&Ah[srow][skh]     = make_uint4(wh[0], wh[1], wh[2], wh[3]);
        *(uint4*)&Ah[srow][skh + 8] = make_uint4(wh[4], wh[5], wh[6], wh[7]);
        *(uint4*)&Bh[bcol][bch] = pbh;
        *(uint4*)&Bl[bcol][bch] = pbl;
        __syncthreads();

        if (k0 + 32 < DD) {
            #pragma unroll
            for (int c = 0; c < 4; ++c)
                pa[c] = *(const float4*)(ap + k0 + 32 + c * 4);
            pbh = *(const uint4*)(bph + k0 + 32);
            pbl = *(const uint4*)(bpl + k0 + 32);
        }

        bf16x8 fah[4], fbh[2], fbl[2];
        #pragma unroll
        for (int i = 0; i < 4; ++i)
            fah[i] = *(const bf16x8*)&Ah[wr * 64 + i * 16 + l15][lko];
        #pragma unroll
        for (int j = 0; j < 2; ++j) {
            fbh[j] = *(const bf16x8*)&Bh[wc * 32 + j * 16 + l15][lko];
            fbl[j] = *(const bf16x8*)&Bl[wc * 32 + j * 16 + l15][lko];
        }
        #pragma unroll
        for (int i = 0; i < 4; ++i) {
            #pragma unroll
            for (int j = 0; j < 2; ++j) {
                acc[i][j] = __builtin_amdgcn_mfma_f32_16x16x32_bf16(
                    fah[i], fbh[j], acc[i][j], 0, 0, 0);
                acc[i][j] = __builtin_amdgcn_mfma_f32_16x16x32_bf16(
                    fah[i], fbl[j], acc[i][j], 0, 0, 0);
            }
        }
        __syncthreads();
    }

    #pragma unroll
    for (int i = 0; i < 4; ++i) {
        int rbase = row0 + wr * 64 + i * 16 + (lane >> 4) * 4;
        #pragma unroll
        for (int j = 0; j < 2; ++j) {
            int gc = col0 + wc * 32 + j * 16 + l15;
            float bc = b_leaf[gc];
            #pragma unroll
            for (int q = 0; q < 4; ++q)
                leaf_pre[(size_t)(rbase + q) * SZ + gc] =
                    fmaxf(acc[i][j][q] + bc, 0.f);
        }
    }
}

// leaf_norm: normalize rows, write chart_h f32 + Hchart bf16 + Sarr=0.
__global__ __launch_bounds__(256) void leaf_norm(
    const float* __restrict__ leaf_pre, float* __restrict__ chart_h,
    u16* __restrict__ Hchart, float* __restrict__ Sarr)
{
    const int r = blockIdx.x;               // 0..1535 = b*32+pos
    const int b = r >> 5, pos = r & 31;
    const int cell = b * NCELLS + pos;
    const int t = threadIdx.x, lane = t & 63, wave = t >> 6;
    __shared__ float red[4];

    float2 v = *(const float2*)&leaf_pre[(size_t)r * SZ + 2 * t];
    float sq = v.x * v.x + v.y * v.y;
    #pragma unroll
    for (int o = 32; o; o >>= 1) sq += __shfl_xor(sq, o);
    if (lane == 0) red[wave] = sq;
    __syncthreads();
    float nrm = sqrtf(red[0] + red[1] + red[2] + red[3]);
    float inv = 1.f / fmaxf(nrm, 1e-12f);
    v.x *= inv; v.y *= inv;
    *(float2*)&chart_h[(size_t)cell * SZ + 2 * t] = v;
    ((u32*)Hchart)[(size_t)cell * 256 + t] = pack2(f2bf(v.x), f2bf(v.y));
    if (t == 0) Sarr[cell] = 0.f;
}

// ---------------------------------------------------------------------------
// transform_mfma: ACU[cell][0:1536] (bf16) = h[cell] @ Wcat [+ b_comp on A].
// 64x64 tile, 4 waves (2x2), wave 32x32, BK=32, XCD-pinned col-tiles.
// ---------------------------------------------------------------------------
__global__ __launch_bounds__(256) void transform_mfma(
    const u16* __restrict__ Hchart, const u16* __restrict__ WT,
    const float* __restrict__ b_comp,
    u16* __restrict__ ACU, int level, int nrt)
{
    __shared__ u16 Ah[64][40];
    __shared__ u16 Bh[64][40];
    __shared__ int cidx[64];

    const int L = TT - level, rows = BB * L, off = off_of(level);
    const int id = blockIdx.x;
    const int w = (id & 7) * (3 * nrt) + (id >> 3);
    const int ct = w / nrt, rt = w % nrt;
    const int col0 = ct * 64;

    const int t = threadIdx.x;
    if (t < 64) {
        int g = rt * 64 + t;
        cidx[t] = (g < rows) ? ((g / L) * NCELLS + off + (g % L)) : -1;
    }

    const int srow = t >> 2, skc = (t & 3) * 8;
    int ga = rt * 64 + srow;
    if (ga >= rows) ga = rows - 1;          // clamp: safe read, store guarded
    const int acell = (ga / L) * NCELLS + off + (ga % L);
    const u16* aph = Hchart + (size_t)acell * SZ + skc;
    const u16* bph = WT + (size_t)(col0 + srow) * SZ + skc;

    const int lane = t & 63, wv = t >> 6;
    const int wr = wv >> 1, wc = wv & 1;
    const int l15 = lane & 15, lko = (lane >> 4) * 8;

    f32x4 acc[2][2];
    #pragma unroll
    for (int i = 0; i < 2; ++i)
        #pragma unroll
        for (int j = 0; j < 2; ++j)
            #pragma unroll
            for (int e = 0; e < 4; ++e) acc[i][j][e] = 0.f;

    uint4 pah = *(const uint4*)aph;
    uint4 pbh = *(const uint4*)bph;

    for (int k0 = 0; k0 < SZ; k0 += 32) {
        *(uint4*)&Ah[srow][skc] = pah;
        *(uint4*)&Bh[srow][skc] = pbh;
        __syncthreads();

        if (k0 + 32 < SZ) {
            pah = *(const uint4*)(aph + k0 + 32);
            pbh = *(const uint4*)(bph + k0 + 32);
        }

        bf16x8 fah[2], fbh[2];
        #pragma unroll
        for (int i = 0; i < 2; ++i)
            fah[i] = *(const bf16x8*)&Ah[wr * 32 + i * 16 + l15][lko];
        #pragma unroll
        for (int j = 0; j < 2; ++j)
            fbh[j] = *(const bf16x8*)&Bh[wc * 32 + j * 16 + l15][lko];
        #pragma unroll
        for (int i = 0; i < 2; ++i)
            #pragma unroll
            for (int j = 0; j < 2; ++j)
                acc[i][j] = __builtin_amdgcn_mfma_f32_16x16x32_bf16(
                    fah[i], fbh[j], acc[i][j], 0, 0, 0);
        __syncthreads();
    }

    #pragma unroll
    for (int i = 0; i < 2; ++i) {
        int rbase = wr * 32 + i * 16 + (lane >> 4) * 4;
        #pragma unroll
        for (int j = 0; j < 2; ++j) {
            int gc = col0 + wc * 32 + j * 16 + l15;
            float bias = (gc < 512) ? b_comp[gc] : 0.f;  // fold comp bias into A
            #pragma unroll
            for (int q = 0; q < 4; ++q) {
                int ci = cidx[rbase + q];
                if (ci >= 0)
                    ACU[(size_t)ci * 1536 + gc] = f2bf(acc[i][j][q] + bias);
            }
        }
    }
}

// ---------------------------------------------------------------------------
// Combine: 512 threads (8 waves) per cell; XCD-swizzled for b-locality.
// bf16 ACU/Hchart reads. A carries the comp bias.
// ---------------------------------------------------------------------------
__global__ __launch_bounds__(512) void combine_kernel(
    float* __restrict__ chart_h, const u16* __restrict__ ACU,
    const u16* __restrict__ Hchart,
    float* __restrict__ Sarr, u16* __restrict__ Hchart_w, int level)
{
    const int L = TT - level, N = level;
    // XCD swizzle: grid C = 48L is divisible by 8; XCD x gets b in [6x, 6x+6)
    const int cpx = (BB * L) >> 3;
    const int swz = (blockIdx.x & 7) * cpx + (blockIdx.x >> 3);
    const int b = swz / L, pos = swz % L;
    const int off = off_of(level);

    __shared__ float s_lds[32], p_lds[32], spre[32];
    __shared__ int lcell[32], rcell[32];
    __shared__ float hred[8][512];
    __shared__ float red[8];

    const int t = threadIdx.x, lane = t & 63, wv = t >> 6;

    if (t < N) {
        int lc = b * NCELLS + off_of(t) + pos;
        int rc = b * NCELLS + off_of(level - t - 1) + pos + t + 1;
        lcell[t] = lc;
        rcell[t] = rc;
        spre[t] = Sarr[lc] + Sarr[rc];
    }
    __syncthreads();

    // phase 1: s_n = u_l . h_r + s_l + s_r  (bf16, 8 vals/lane, n += 8)
    for (int n = wv; n < N; n += 8) {
        const u16* u  = ACU + (size_t)lcell[n] * 1536 + 1024;
        const u16* hr = Hchart + (size_t)rcell[n] * SZ;
        uint4 uv = *(const uint4*)&u[lane * 8];
        uint4 hv = *(const uint4*)&hr[lane * 8];
        float d = 0.f;
        {
            float2 a = upk(uv.x), h2 = upk(hv.x);
            d = fmaf(a.x, h2.x, fmaf(a.y, h2.y, d));
        }
        {
            float2 a = upk(uv.y), h2 = upk(hv.y);
            d = fmaf(a.x, h2.x, fmaf(a.y, h2.y, d));
        }
        {
            float2 a = upk(uv.z), h2 = upk(hv.z);
            d = fmaf(a.x, h2.x, fmaf(a.y, h2.y, d));
        }
        {
            float2 a = upk(uv.w), h2 = upk(hv.w);
            d = fmaf(a.x, h2.x, fmaf(a.y, h2.y, d));
        }
        #pragma unroll
        for (int o = 32; o; o >>= 1) d += __shfl_xor(d, o);
        if (lane == 0) s_lds[n] = d + spre[n];
    }
    __syncthreads();

    // phase 1b: softmax + sbar (wave 0)
    if (wv == 0) {
        float sv = (lane < N) ? s_lds[lane] : -INFINITY;
        float m = sv;
        #pragma unroll
        for (int o = 32; o; o >>= 1) m = fmaxf(m, __shfl_xor(m, o));
        float e = (lane < N) ? expf(sv - m) : 0.f;
        float sum = e;
        #pragma unroll
        for (int o = 32; o; o >>= 1) sum += __shfl_xor(sum, o);
        float p = e / sum;
        if (lane < N) p_lds[lane] = p;
        float sb = (lane < N) ? sv * p : 0.f;
        #pragma unroll
        for (int o = 32; o; o >>= 1) sb += __shfl_xor(sb, o);
        if (lane == 0) Sarr[(size_t)b * NCELLS + off + pos] = sb;
    }
    __syncthreads();

    // phase 2: per-wave partial hbar; lane owns 8 consecutive outputs
    float hacc[8];
    #pragma unroll
    for (int q = 0; q < 8; ++q) hacc[q] = 0.f;
    for (int n = wv; n < N; n += 8) {
        const u16* A_ = ACU + (size_t)lcell[n] * 1536;
        const u16* C_ = ACU + (size_t)rcell[n] * 1536 + 512;
        uint4 va = *(const uint4*)&A_[lane * 8];
        uint4 vc = *(const uint4*)&C_[lane * 8];
        float p = p_lds[n];
        const u32 av[4] = {va.x, va.y, va.z, va.w};
        const u32 cv[4] = {vc.x, vc.y, vc.z, vc.w};
        #pragma unroll
        for (int c = 0; c < 4; ++c) {
            float2 a2 = upk(av[c]);
            float2 c2 = upk(cv[c]);
            hacc[c * 2]     = fmaf(p, fmaxf(a2.x + c2.x, 0.f), hacc[c * 2]);
            hacc[c * 2 + 1] = fmaf(p, fmaxf(a2.y + c2.y, 0.f), hacc[c * 2 + 1]);
        }
    }
    *(float4*)&hred[wv][lane * 8]     = *(float4*)&hacc[0];
    *(float4*)&hred[wv][lane * 8 + 4] = *(float4*)&hacc[4];
    __syncthreads();

    // final: thread t owns output t (512 threads)
    float hv = hred[0][t] + hred[1][t] + hred[2][t] + hred[3][t]
             + hred[4][t] + hred[5][t] + hred[6][t] + hred[7][t];

    float sq = hv * hv;
    #pragma unroll
    for (int o = 32; o; o >>= 1) sq += __shfl_xor(sq, o);
    if (lane == 0) red[wv] = sq;
    __syncthreads();
    float nrm = sqrtf(((red[0] + red[1]) + (red[2] + red[3]))
                    + ((red[4] + red[5]) + (red[6] + red[7])));
    float inv = 1.f / fmaxf(nrm, 1e-12f);
    hv *= inv;
    hred[0][t] = hv;
    __syncthreads();
    const int ocell = b * NCELLS + off + pos;
    if (t < 256) {
        float x0 = hred[0][2 * t], x1 = hred[0][2 * t + 1];
        *(float2*)&chart_h[(size_t)ocell * SZ + 2 * t] = make_float2(x0, x1);
        ((u32*)Hchart_w)[(size_t)ocell * 256 + t] = pack2(f2bf(x0), f2bf(x1));
    }
}

// ---------------------------------------------------------------------------
extern "C" void kernel_launch(void* const* d_in, const int* in_sizes, int n_in,
                              void* d_out, int out_size, void* d_ws, size_t ws_size,
                              hipStream_t stream)
{
    const float* x      = (const float*)d_in[0];
    const float* w_leaf = (const float*)d_in[1];
    const float* b_leaf = (const float*)d_in[2];
    const float* w_comp = (const float*)d_in[3];
    const float* b_comp = (const float*)d_in[4];
    const float* s_bil  = (const float*)d_in[5];
    float* chart_h = (float*)d_out;

    char* ws = (char*)d_ws;
    u16* ACU    = (u16*)ws;                        ws += (size_t)BB * NCELLS * 1536 * 2;
    u16* Hchart = (u16*)ws;                        ws += (size_t)BB * NCELLS * SZ * 2;
    float* Sarr = (float*)ws;                      ws += (size_t)BB * NCELLS * 4;
    u16* WT     = (u16*)ws;                        ws += (size_t)1536 * SZ * 2;
    u16* WLT_hi = (u16*)ws;                        ws += (size_t)SZ * DD * 2;
    u16* WLT_lo = (u16*)ws;                        ws += (size_t)SZ * DD * 2;
    float* leaf_pre = (float*)ws;                  ws += (size_t)BB * TT * SZ * 4;

    prep_w<<<(1536 * SZ) / 256, 256, 0, stream>>>(w_comp, s_bil, WT);
    prep_wl<<<(SZ * DD) / 256, 256, 0, stream>>>(w_leaf, WLT_hi, WLT_lo);
    leaf_mfma<<<dim3(8, 12), 256, 0, stream>>>(x, WLT_hi, WLT_lo, b_leaf, leaf_pre);
    leaf_norm<<<BB * TT, 256, 0, stream>>>(leaf_pre, chart_h, Hchart, Sarr);

    {
        int nrt = (BB * TT + 63) / 64;   // 24
        transform_mfma<<<24 * nrt, 256, 0, stream>>>(
            Hchart, WT, b_comp, ACU, 0, nrt);
    }

    for (int level = 1; level < TT; ++level) {
        int L = TT - level;
        combine_kernel<<<BB * L, 512, 0, stream>>>(
            chart_h, ACU, Hchart, Sarr, Hchart, level);
        if (level < TT - 1) {
            int nrt = (BB * L + 63) / 64;
            transform_mfma<<<24 * nrt, 256, 0, stream>>>(
                Hchart, WT, b_comp, ACU, level, nrt);
        }
    }
}